// Round 7
// baseline (1337.579 us; speedup 1.0000x reference)
//
#include <hip/hip_runtime.h>
#include <math.h>

#define DEV __device__ __forceinline__

DEV float fexp(float x){ return __expf(x); }
DEV float elu_(float x){ return x > 0.f ? x : fexp(x) - 1.f; }
DEV float sigm_(float x){ return 1.f/(1.f + fexp(-x)); }
DEV float tanh_(float x){ float e = fexp(2.f*x); return 1.f - 2.f/(e + 1.f); }
DEV unsigned bf16r(float x){ unsigned u = __float_as_uint(x);
  return (u + 0x7fffu + ((u>>16)&1u)) >> 16; }
DEV float blo(unsigned u){ return __uint_as_float(u << 16); }
DEV float bhi(unsigned u){ return __uint_as_float(u & 0xffff0000u); }
DEV float bl(unsigned short u){ return __uint_as_float(((unsigned)u) << 16); }

using frag  = __attribute__((ext_vector_type(8))) short;   // 8 bf16 (4 VGPRs)
using f32x4 = __attribute__((ext_vector_type(4))) float;   // MFMA acc

// ---------------------------------------------------------------------------
// init: stack=0, pvecA=[1,0..], mem=0, c_prev=tile(c_0), softmax op-weights
// (part67 needs no zeroing: every slot is written each t)
// ---------------------------------------------------------------------------
__global__ __launch_bounds__(256)
void init_k(const float* __restrict__ c0, const float* __restrict__ c3ow,
            const float* __restrict__ c4ow, const float* __restrict__ aow,
            float* __restrict__ stack, float* __restrict__ pvecA,
            float* __restrict__ mem, float* __restrict__ cprev,
            float* __restrict__ swb)
{
  int idx = blockIdx.x*256 + threadIdx.x;
  int stride = gridDim.x*256;
  for (int i = idx; i < 64*150*8; i += stride) stack[i] = 0.f;
  for (int i = idx; i < 64*8;    i += stride) pvecA[i] = ((i & 7) == 0) ? 1.f : 0.f;
  for (int i = idx; i < 64*512;  i += stride) mem[i] = 0.f;
  for (int i = idx; i < 64*512;  i += stride) cprev[i] = c0[i & 511];
  if (idx < 8) {
    const float* ow = (idx < 4) ? (c3ow + idx*6)
                    : (idx < 6) ? (c4ow + (idx-4)*6)
                                : (aow  + (idx-6)*6);
    float mx = ow[0];
    for (int m = 1; m < 6; ++m) mx = fmaxf(mx, ow[m]);
    float e[6]; float s = 0.f;
    for (int m = 0; m < 6; ++m) { e[m] = fexp(ow[m]-mx); s += e[m]; }
    for (int m = 0; m < 6; ++m) swb[idx*6+m] = e[m]/s;
  }
}

// ---------------------------------------------------------------------------
// pack Wh (both dirs) into uint4 of 4 bf16-pairs (LSTM recurrent weights)
// ---------------------------------------------------------------------------
__global__ __launch_bounds__(256)
void pack4_k(const float* __restrict__ Whf, const float* __restrict__ Whb,
             uint4* __restrict__ whp4)
{
  int idx = blockIdx.x*256 + threadIdx.x;   // 2*32*1024
  int dir = idx >> 15;
  int rem = idx & 32767;
  int kg  = rem >> 10;
  int n   = rem & 1023;
  const float* Wh = dir ? Whb : Whf;
  unsigned v[4];
#pragma unroll
  for (int j = 0; j < 4; ++j) {
    int k = kg*8 + 2*j;
    float lo = Wh[(size_t)k*1024 + n];
    float hi = Wh[(size_t)(k+1)*1024 + n];
    v[j] = bf16r(lo) | (bf16r(hi) << 16);
  }
  whp4[idx] = make_uint4(v[0], v[1], v[2], v[3]);
}

// ---------------------------------------------------------------------------
// pair-pack t2m: out[k*256+c] = bf16(W[k][c]) | bf16(W[k][c+256])<<16
// ---------------------------------------------------------------------------
__global__ __launch_bounds__(256)
void packPair_k(const float* __restrict__ W, unsigned* __restrict__ outp)
{
  int idx = blockIdx.x*256 + threadIdx.x;   // 512*256
  int k = idx >> 8, c = idx & 255;
  outp[idx] = bf16r(W[(size_t)k*512 + c]) | (bf16r(W[(size_t)k*512 + 256 + c]) << 16);
}

// ---------------------------------------------------------------------------
// B-pack into MFMA fragment-native bf16 layout
// ---------------------------------------------------------------------------
__global__ __launch_bounds__(256)
void packB_k(const float* __restrict__ W, short* __restrict__ Bp,
             int KC, int Ng, int Ksrc, int N, int trans)
{
  int idx = blockIdx.x*256 + threadIdx.x;
  if (idx >= KC*Ng*64) return;
  int lane = idx & 63;
  int g    = (idx >> 6) % Ng;
  int kc   = idx / (64*Ng);
  int n = g*16 + (lane & 15);
  int kb = kc*32 + ((lane >> 4) << 3);
  unsigned o[4];
#pragma unroll
  for (int jj = 0; jj < 4; ++jj) {
    int k0 = kb + 2*jj;
    float v0 = (k0   < Ksrc) ? (trans ? W[(size_t)n*Ksrc + k0]   : W[(size_t)(k0)*N + n])   : 0.f;
    float v1 = (k0+1 < Ksrc) ? (trans ? W[(size_t)n*Ksrc + k0+1] : W[(size_t)(k0+1)*N + n]) : 0.f;
    o[jj] = bf16r(v0) | (bf16r(v1) << 16);
  }
  *(uint4*)(Bp + (size_t)idx*8) = make_uint4(o[0], o[1], o[2], o[3]);
}

// ---------------------------------------------------------------------------
__global__ __launch_bounds__(256)
void packImg_k(const float* __restrict__ image, short* __restrict__ Ap)
{
  int idx = blockIdx.x*256 + threadIdx.x;   // 600*20*64
  int lane = idx & 63;
  int kc   = (idx >> 6) % 20;
  int mt   = idx / 1280;
  int row = mt*16 + (lane & 15);
  int b = row / 150, p = row % 150;
  int cb = kc*32 + ((lane >> 4) << 3);
  unsigned o[4];
#pragma unroll
  for (int jj = 0; jj < 4; ++jj) {
    float v0 = image[((size_t)b*640 + cb + 2*jj    )*150 + p];
    float v1 = image[((size_t)b*640 + cb + 2*jj + 1)*150 + p];
    o[jj] = bf16r(v0) | (bf16r(v1) << 16);
  }
  *(uint4*)(Ap + (size_t)idx*8) = make_uint4(o[0], o[1], o[2], o[3]);
}

// ---------------------------------------------------------------------------
__global__ __launch_bounds__(256)
void packEmb_k(const float* __restrict__ embedW, const int* __restrict__ ques,
               short* __restrict__ Ap)
{
  int idx = blockIdx.x*256 + threadIdx.x;   // 120*10*64
  int lane = idx & 63;
  int kc   = (idx >> 6) % 10;
  int mt   = idx / 640;
  int row = mt*16 + (lane & 15);
  int q = ques[row];
  int kb = kc*32 + ((lane >> 4) << 3);
  unsigned o[4];
#pragma unroll
  for (int jj = 0; jj < 4; ++jj) {
    int k0 = kb + 2*jj;
    float v0 = (k0   < 300) ? embedW[(size_t)q*300 + k0]   : 0.f;
    float v1 = (k0+1 < 300) ? embedW[(size_t)q*300 + k0+1] : 0.f;
    o[jj] = bf16r(v0) | (bf16r(v1) << 16);
  }
  *(uint4*)(Ap + (size_t)idx*8) = make_uint4(o[0], o[1], o[2], o[3]);
}

// ---------------------------------------------------------------------------
// MFMA GEMM. mode 0: fp32 row-major; mode 1: bf16 A-pack; mode 2: bf16 row-major
// ---------------------------------------------------------------------------
__global__ __launch_bounds__(256)
void gemmM_k(const short* __restrict__ Ap, const short* __restrict__ Bp,
             const float* __restrict__ bias, void* __restrict__ Cout,
             int KC, int Ng, int N, int mode, int act, int KCout)
{
  __shared__ float lds[4][16][68];
  const int tid = threadIdx.x, lane = tid & 63, w = tid >> 6;
  const int mt = blockIdx.y*4 + w;
  const int ncol0 = blockIdx.x*64;
  const short* Abase = Ap + (((size_t)mt*KC) << 9) + lane*8;
  const short* Bbase = Bp + (((size_t)blockIdx.x*4) << 9) + lane*8;
  f32x4 acc0 = {0.f,0.f,0.f,0.f}, acc1 = acc0, acc2 = acc0, acc3 = acc0;
#pragma unroll 2
  for (int kc = 0; kc < KC; ++kc) {
    frag a = *(const frag*)(Abase + ((size_t)kc << 9));
    const short* bk = Bbase + (((size_t)kc*Ng) << 9);
    frag b0 = *(const frag*)(bk);
    frag b1 = *(const frag*)(bk + 512);
    frag b2 = *(const frag*)(bk + 1024);
    frag b3 = *(const frag*)(bk + 1536);
    acc0 = __builtin_amdgcn_mfma_f32_16x16x32_bf16(a, b0, acc0, 0, 0, 0);
    acc1 = __builtin_amdgcn_mfma_f32_16x16x32_bf16(a, b1, acc1, 0, 0, 0);
    acc2 = __builtin_amdgcn_mfma_f32_16x16x32_bf16(a, b2, acc2, 0, 0, 0);
    acc3 = __builtin_amdgcn_mfma_f32_16x16x32_bf16(a, b3, acc3, 0, 0, 0);
  }
  {
    int colb = lane & 15, rowb = (lane >> 4)*4;
#pragma unroll
    for (int r = 0; r < 4; ++r) {
      lds[w][rowb+r][ 0+colb] = acc0[r];
      lds[w][rowb+r][16+colb] = acc1[r];
      lds[w][rowb+r][32+colb] = acc2[r];
      lds[w][rowb+r][48+colb] = acc3[r];
    }
  }
  __syncthreads();
  if (mode == 0) {
    float* C = (float*)Cout;
    int mloc = lane >> 2, q4 = lane & 3;
    size_t rowoff = (size_t)(mt*16 + mloc)*N + ncol0 + q4*16;
#pragma unroll
    for (int i = 0; i < 4; ++i) {
      float4 v = *(float4*)&lds[w][mloc][q4*16 + i*4];
      const float* bp = bias + ncol0 + q4*16 + i*4;
      v.x += bp[0]; v.y += bp[1]; v.z += bp[2]; v.w += bp[3];
      if (act) { v.x = elu_(v.x); v.y = elu_(v.y); v.z = elu_(v.z); v.w = elu_(v.w); }
      *(float4*)&C[rowoff + i*4] = v;
    }
  } else if (mode == 1) {
    short* C = (short*)Cout;
    int m = lane & 15, qb = (lane >> 4)*8;
#pragma unroll
    for (int h = 0; h < 2; ++h) {
      int nl = h*32 + qb;
      unsigned o[4];
#pragma unroll
      for (int jj = 0; jj < 4; ++jj) {
        float v0 = lds[w][m][nl + 2*jj]     + bias[ncol0 + nl + 2*jj];
        float v1 = lds[w][m][nl + 2*jj + 1] + bias[ncol0 + nl + 2*jj + 1];
        if (act) { v0 = elu_(v0); v1 = elu_(v1); }
        o[jj] = bf16r(v0) | (bf16r(v1) << 16);
      }
      *(uint4*)(C + (((size_t)mt*KCout + (ncol0 >> 5) + h) << 9) + lane*8)
          = make_uint4(o[0], o[1], o[2], o[3]);
    }
  } else {
    unsigned short* C = (unsigned short*)Cout;
    int row = lane >> 2, cb = (lane & 3)*16;
#pragma unroll
    for (int h = 0; h < 2; ++h) {
      unsigned o[4];
#pragma unroll
      for (int jj = 0; jj < 4; ++jj) {
        float v0 = lds[w][row][cb + h*8 + 2*jj]     + bias[ncol0 + cb + h*8 + 2*jj];
        float v1 = lds[w][row][cb + h*8 + 2*jj + 1] + bias[ncol0 + cb + h*8 + 2*jj + 1];
        if (act) { v0 = elu_(v0); v1 = elu_(v1); }
        o[jj] = bf16r(v0) | (bf16r(v1) << 16);
      }
      *(uint4*)&C[(size_t)(mt*16 + row)*N + ncol0 + cb + h*8]
          = make_uint4(o[0], o[1], o[2], o[3]);
    }
  }
}

// ---------------------------------------------------------------------------
// 64-row batch GEMM, K-split across waves (latency-optimized)
// ---------------------------------------------------------------------------
__global__ __launch_bounds__(512)
void gemm64b_k(const float* __restrict__ A1, long zA1, int K1log,
               const float* __restrict__ A2, int K2,
               const float* __restrict__ B, long zB,
               const float* __restrict__ bias, int zbias,
               float* __restrict__ C, long zC, int N, int act)
{
  const int K1 = 1 << K1log;
  const int Kt = K1 + K2;
  __shared__ __align__(16) float As[8][1024];
  __shared__ float part[8][8][64];
  const int tid = threadIdx.x;
  const int z = blockIdx.z;
  const int r0 = blockIdx.y*8;
  {
    const float* a1 = A1 + (size_t)z*zA1;
    const int nf4 = (8*K1) >> 2;
    for (int e4 = tid; e4 < nf4; e4 += 512) {
      int r = e4 >> (K1log-2);
      int k4 = (e4 & ((K1>>2)-1)) << 2;
      *(float4*)&As[r][k4] = *(const float4*)&a1[(size_t)(r0+r)*K1 + k4];
    }
    if (K2 > 0) {
      for (int e4 = tid; e4 < 1024; e4 += 512) {
        int r = e4 >> 7;
        int k4 = (e4 & 127) << 2;
        *(float4*)&As[r][K1+k4] = *(const float4*)&A2[(size_t)(r0+r)*512 + k4];
      }
    }
  }
  __syncthreads();
  const int lane = tid & 63, w = tid >> 6;
  const int n = blockIdx.x*64 + lane;
  const bool nv = n < N;
  const int kseg = Kt >> 3;
  const int k0 = w*kseg;
  const float* Bp = B + (size_t)z*zB + (size_t)k0*N + (nv ? n : 0);
  float acc[8] = {0,0,0,0,0,0,0,0};
#pragma unroll 8
  for (int kk = 0; kk < kseg; ++kk) {
    float bv = nv ? Bp[(size_t)kk*N] : 0.f;
    int k = k0 + kk;
#pragma unroll
    for (int r = 0; r < 8; ++r) acc[r] += As[r][k]*bv;
  }
#pragma unroll
  for (int r = 0; r < 8; ++r) part[w][r][lane] = acc[r];
  __syncthreads();
  {
    int r = tid >> 6, c = tid & 63;
    int nn = blockIdx.x*64 + c;
    if (nn < N) {
      float s = 0.f;
#pragma unroll
      for (int w2 = 0; w2 < 8; ++w2) s += part[w2][r][c];
      s += bias ? bias[(size_t)z*zbias + nn] : 0.f;
      if (act == 1) s = elu_(s);
      C[(size_t)z*zC + (size_t)(r0+r)*N + nn] = s;
    }
  }
}

// ---------------------------------------------------------------------------
// bidirectional masked LSTM; 128 blocks = (dir, batch); Wh as uint4 bf16-pairs
// ---------------------------------------------------------------------------
__global__ __launch_bounds__(1024)
void lstm4_k(const float* __restrict__ xWf, const float* __restrict__ xWb,
             const uint4* __restrict__ whp4,
             const int* __restrict__ qlen, float* __restrict__ lstm_out,
             float* __restrict__ qout)
{
  int dir = blockIdx.x >> 6;
  int b   = blockIdx.x & 63;
  const float* xW = dir ? xWb : xWf;
  const uint4* Wp = whp4 + (size_t)dir*32768 + threadIdx.x;
  __shared__ __align__(16) float hl[256];
  __shared__ __align__(16) float cl[256];
  __shared__ float zl[1024];
  int tid = threadIdx.x;
  if (tid < 256) { hl[tid] = 0.f; cl[tid] = 0.f; }
  int len = qlen[b];
  for (int ss = 0; ss < 30; ++ss) {
    int s = dir ? (29-ss) : ss;
    __syncthreads();
    float z = xW[((size_t)b*30 + s)*1024 + tid];
#pragma unroll 4
    for (int kg = 0; kg < 32; ++kg) {
      uint4 w = Wp[(size_t)kg*1024];
      float4 ha = *(const float4*)&hl[kg*8];
      float4 hb = *(const float4*)&hl[kg*8+4];
      z += ha.x*blo(w.x) + ha.y*bhi(w.x) + ha.z*blo(w.y) + ha.w*bhi(w.y)
         + hb.x*blo(w.z) + hb.y*bhi(w.z) + hb.z*blo(w.w) + hb.w*bhi(w.w);
    }
    zl[tid] = z;
    __syncthreads();
    if (tid < 256) {
      float iv = zl[tid], fv = zl[256+tid], gv = zl[512+tid], ov = zl[768+tid];
      float cn = sigm_(fv)*cl[tid] + sigm_(iv)*tanh_(gv);
      float hn = sigm_(ov)*tanh_(cn);
      bool m = s < len;
      lstm_out[((size_t)b*30 + s)*512 + dir*256 + tid] = m ? hn : 0.f;
      if (m) { hl[tid] = hn; cl[tid] = cn; }
    }
  }
  __syncthreads();
  if (tid < 256) qout[(size_t)b*512 + dir*256 + tid] = hl[tid];
}

// ---------------------------------------------------------------------------
// fused kc + attn + tmap: w[9]+entropy; attention context -> cprev (and LDS);
// tmap = c @ t2m (bf16 pair-packed) -> tmapv
// ---------------------------------------------------------------------------
__global__ __launch_bounds__(256)
void kcattn2_k(const float* __restrict__ u, const float* __restrict__ Wmod,
               const float* __restrict__ lstm_out, const float* __restrict__ W3,
               const unsigned* __restrict__ t2pp, const float* __restrict__ t2mb,
               float* __restrict__ wout, float* __restrict__ imp_part,
               float* __restrict__ cout, float* __restrict__ tmapv, int t)
{
  int b = blockIdx.x;
  int lane = threadIdx.x & 63, wave = threadIdx.x >> 6;
  __shared__ float ush[512];
  __shared__ float sC[512];
  __shared__ float wl[9];
  __shared__ float sc[32], at[32];
  ush[threadIdx.x]     = u[b*512 + threadIdx.x];
  ush[256+threadIdx.x] = u[b*512 + 256 + threadIdx.x];
  __syncthreads();
  for (int m = wave; m < 9; m += 4) {
    float acc = 0.f;
    for (int k = lane; k < 512; k += 64) acc += ush[k]*Wmod[k*9+m];
#pragma unroll
    for (int off = 32; off; off >>= 1) acc += __shfl_down(acc, off);
    if (lane == 0) wl[m] = acc;
  }
  for (int s = wave; s < 30; s += 4) {
    float acc = 0.f;
    const float* lo = lstm_out + ((size_t)b*30 + s)*512;
    for (int h = lane; h < 512; h += 64) acc += lo[h]*ush[h]*W3[h];
#pragma unroll
    for (int off = 32; off; off >>= 1) acc += __shfl_down(acc, off);
    if (lane == 0) sc[s] = acc;
  }
  __syncthreads();
  if (threadIdx.x == 0) {
    float mx = wl[0];
    for (int m = 1; m < 9; ++m) mx = fmaxf(mx, wl[m]);
    float s = 0.f;
    for (int m = 0; m < 9; ++m) s += fexp(wl[m]-mx);
    float ls = logf(s);
    float ent = 0.f;
    for (int m = 0; m < 9; ++m) {
      float l = wl[m]-mx-ls;
      float w = fexp(l);
      wout[b*9+m] = w;
      ent -= w*l;
    }
    imp_part[t*64+b] = ent;
  }
  if (wave == 1) {
    float v = (lane < 30) ? sc[lane] : -3.4e38f;
    float mx = v;
#pragma unroll
    for (int off = 32; off; off >>= 1) mx = fmaxf(mx, __shfl_xor(mx, off));
    float e = (lane < 30) ? fexp(v-mx) : 0.f;
    float ssum = e;
#pragma unroll
    for (int off = 32; off; off >>= 1) ssum += __shfl_xor(ssum, off);
    if (lane < 30) at[lane] = e/ssum;
  }
  __syncthreads();
  for (int h = threadIdx.x; h < 512; h += 256) {
    float acc = 0.f;
#pragma unroll 6
    for (int s = 0; s < 30; ++s) acc += at[s]*lstm_out[((size_t)b*30 + s)*512 + h];
    cout[b*512+h] = acc;
    sC[h] = acc;
  }
  __syncthreads();
  // tmap = c @ t2m + b  (pair-packed bf16: cols tid and tid+256)
  {
    float a0 = 0.f, a1 = 0.f;
    const unsigned* tp = t2pp + threadIdx.x;
#pragma unroll 8
    for (int k = 0; k < 512; ++k) {
      float cv = sC[k];
      unsigned wv2 = tp[(size_t)k*256];
      a0 += cv*blo(wv2);
      a1 += cv*bhi(wv2);
    }
    tmapv[b*512 + threadIdx.x]       = a0 + t2mb[threadIdx.x];
    tmapv[b*512 + 256 + threadIdx.x] = a1 + t2mb[256 + threadIdx.x];
  }
}

// ---------------------------------------------------------------------------
// fused modules + pooled partials (plain stores, NO atomics) + stack update
// + pvec ping-pong.  grid (64 b, 19 pb).
// part67 layout: [b][pb][2][512]
// ---------------------------------------------------------------------------
__global__ __launch_bounds__(256)
void modules2_k(const unsigned short* __restrict__ imapB, const float* __restrict__ tmapv,
                float* __restrict__ stack, const float* __restrict__ pvecIn,
                float* __restrict__ pvecOut,
                const float* __restrict__ swb, const float* __restrict__ c3w,
                const float* __restrict__ c3b, const float* __restrict__ c4w,
                const float* __restrict__ c4b, const float* __restrict__ wmod,
                float* __restrict__ part67)
{
  int b  = blockIdx.x;
  int pb = blockIdx.y;
  int lane = threadIdx.x & 63, wave = threadIdx.x >> 6;
  __shared__ float sT[512];
  __shared__ float pv[8], pd[8], wm[9];
  __shared__ float wpart[4][2][512];
  for (int j = threadIdx.x; j < 512; j += 256) sT[j] = tmapv[b*512 + j];
  if (threadIdx.x < 8) pv[threadIdx.x] = pvecIn[b*8+threadIdx.x];
  if (threadIdx.x >= 64 && threadIdx.x < 73) wm[threadIdx.x-64] = wmod[b*9 + threadIdx.x-64];
  __syncthreads();
  if (threadIdx.x < 8) {
    int l = threadIdx.x;
    pd[l] = (l < 7 ? pv[l+1] : 0.f) + (l == 0 ? pv[0] : 0.f);
  }
  __syncthreads();
  if (pb == 0 && threadIdx.x < 8) {
    int l = threadIdx.x;
    float WP = wm[0]+wm[1]+wm[2]+wm[3] + wm[6] + wm[8];
    float WD = wm[4]+wm[5] + wm[7];
    pvecOut[b*8+l] = WP*pv[l] + WD*pd[l];
  }

  float W[8][6];
#pragma unroll
  for (int m = 0; m < 8; ++m)
#pragma unroll
    for (int i = 0; i < 6; ++i) W[m][i] = swb[m*6+i];
  float W03 = wm[0]+wm[1]+wm[2]+wm[3];
  float W45 = wm[4]+wm[5];

  float acc6[8], acc7[8];
#pragma unroll
  for (int i = 0; i < 8; ++i) { acc6[i] = 0.f; acc7[i] = 0.f; }

  for (int pi = 0; pi < 2; ++pi) {
    int p = pb*8 + wave*2 + pi;
    if (p < 150) {
      const float* st = stack + ((size_t)b*150 + p)*8;
      float a = 0.f, av2 = 0.f;
#pragma unroll
      for (int l = 0; l < 8; ++l) { float v = st[l]; a += v*pv[l]; av2 += v*pd[l]; }
      float part[6] = {0,0,0,0,0,0};
#pragma unroll 2
      for (int i = 0; i < 8; ++i) {
        int d = i*64 + lane;
        float x = bl(imapB[((size_t)b*150 + p)*512 + d]);
        float t = sT[d];
#pragma unroll
        for (int m = 0; m < 4; ++m) {
          float c1 = W[m][0]*t + W[m][1] + W[m][4] + (W[m][2] + W[m][3]*t)*a;
          float c0 = W[m][1]*t + W[m][5]*t*a;
          part[m] += elu_(c1*x + c0) * c3w[m*512+d];
        }
#pragma unroll
        for (int m = 0; m < 2; ++m) {
          float c1 = W[4+m][0]*t + W[4+m][1] + W[4+m][2]*a + W[4+m][3]*av2
                   + W[4+m][4]*a*av2 + W[4+m][5]*t*(a+av2);
          part[4+m] += elu_(c1*x + W[4+m][1]*t) * c4w[m*512+d];
        }
        float c16 = W[6][0]*t + W[6][1] + W[6][4] + (W[6][2] + W[6][3]*t)*a;
        float c06 = W[6][1]*t + W[6][5]*t*a;
        acc6[i] += elu_(c16*x + c06);
        float c17 = W[7][0]*t + W[7][1] + W[7][2]*a + W[7][3]*av2
                  + W[7][4]*a*av2 + W[7][5]*t*(a+av2);
        acc7[i] += elu_(c17*x + W[7][1]*t);
      }
#pragma unroll
      for (int m = 0; m < 6; ++m) {
#pragma unroll
        for (int off = 32; off; off >>= 1) part[m] += __shfl_down(part[m], off);
        part[m] = __shfl(part[m], 0);
      }
      float r3  = wm[0]*(part[0]+c3b[0]) + wm[1]*(part[1]+c3b[1])
                + wm[2]*(part[2]+c3b[2]) + wm[3]*(part[3]+c3b[3]);
      float r45 = wm[4]*(part[4]+c4b[0]) + wm[5]*(part[5]+c4b[1]);
      if (lane < 8) {
        int l = lane;
        size_t idx = ((size_t)b*150 + p)*8 + l;
        stack[idx] = stack[idx]*(1.f - W03*pv[l] - W45*pd[l])
                   + pv[l]*r3 + pd[l]*r45;
      }
    }
  }
#pragma unroll
  for (int i = 0; i < 8; ++i) {
    wpart[wave][0][i*64+lane] = acc6[i];
    wpart[wave][1][i*64+lane] = acc7[i];
  }
  __syncthreads();
  for (int e = threadIdx.x; e < 1024; e += 256) {
    int which = e >> 9, d = e & 511;
    float s = wpart[0][which][d] + wpart[1][which][d]
            + wpart[2][which][d] + wpart[3][which][d];
    part67[(((size_t)b*19 + pb)*2 + which)*512 + d] = s;   // plain store
  }
}

// ---------------------------------------------------------------------------
// fused ans GEMMs (z=0,1; A staged by reducing the 19 pb-partials) +
// mem blend + next-t u GEMM.  grid (8 colchunks, 8 rowchunks), 512 threads.
// ---------------------------------------------------------------------------
__global__ __launch_bounds__(512)
void ansu_k(const float* __restrict__ part67, const float* __restrict__ tmapv,
            const float* __restrict__ ansW, const float* __restrict__ ansb,
            const float* __restrict__ wmw, float* __restrict__ memb,
            const float* __restrict__ tmp1n, const float* __restrict__ cprev,
            const float* __restrict__ W2w, const float* __restrict__ W2b,
            float* __restrict__ ubuf, int do_u)
{
  __shared__ __align__(16) float As[8][1024];
  __shared__ float part[8][8][64];
  __shared__ float m6s[8][64];
  const int tid = threadIdx.x;
  const int r0 = blockIdx.y*8;
  const int nc0 = blockIdx.x*64;
  const int lane = tid & 63, w = tid >> 6;

  for (int z = 0; z < 2; ++z) {
    // stage A: pooled[z][b][d] = (1/150) * sum_pb part67[b][pb][z][d]
    for (int e = tid; e < 4096; e += 512) {
      int r = e >> 9, d = e & 511;
      const float* pp = part67 + (((size_t)(r0+r)*19)*2 + z)*512 + d;
      float acc = 0.f;
#pragma unroll
      for (int pb = 0; pb < 19; ++pb) acc += pp[(size_t)pb*1024];
      As[r][d] = acc * (1.f/150.f);
    }
    for (int e4 = tid; e4 < 1024; e4 += 512) {
      int r = e4 >> 7, k4 = (e4 & 127) << 2;
      *(float4*)&As[r][512+k4] = *(const float4*)&tmapv[(size_t)(r0+r)*512 + k4];
    }
    __syncthreads();
    {
      const float* Bp = ansW + (size_t)z*524288 + (size_t)(w*128)*512 + nc0 + lane;
      float acc[8] = {0,0,0,0,0,0,0,0};
      int k0 = w*128;
#pragma unroll 8
      for (int kk = 0; kk < 128; ++kk) {
        float bv = Bp[(size_t)kk*512];
#pragma unroll
        for (int r = 0; r < 8; ++r) acc[r] += As[r][k0+kk]*bv;
      }
#pragma unroll
      for (int r = 0; r < 8; ++r) part[w][r][lane] = acc[r];
    }
    __syncthreads();
    {
      int r = tid >> 6, c = tid & 63;
      float s = 0.f;
#pragma unroll
      for (int w2 = 0; w2 < 8; ++w2) s += part[w2][r][c];
      s += ansb[z*512 + nc0 + c];
      if (z == 0) {
        m6s[r][c] = s;
      } else {
        int b = r0 + r;
        float w6 = wmw[b*9+6], w7 = wmw[b*9+7];
        memb[(size_t)b*512 + nc0 + c] = w6*m6s[r][c] + w7*s
                                      + (1.f - w6 - w7)*memb[(size_t)b*512 + nc0 + c];
      }
    }
    __syncthreads();
  }

  if (do_u) {
    for (int e4 = tid; e4 < 1024; e4 += 512) {
      int r = e4 >> 7, k4 = (e4 & 127) << 2;
      *(float4*)&As[r][k4]     = *(const float4*)&tmp1n[(size_t)(r0+r)*512 + k4];
      *(float4*)&As[r][512+k4] = *(const float4*)&cprev[(size_t)(r0+r)*512 + k4];
    }
    __syncthreads();
    {
      const float* Bp = W2w + (size_t)(w*128)*512 + nc0 + lane;
      float acc[8] = {0,0,0,0,0,0,0,0};
      int k0 = w*128;
#pragma unroll 8
      for (int kk = 0; kk < 128; ++kk) {
        float bv = Bp[(size_t)kk*512];
#pragma unroll
        for (int r = 0; r < 8; ++r) acc[r] += As[r][k0+kk]*bv;
      }
#pragma unroll
      for (int r = 0; r < 8; ++r) part[w][r][lane] = acc[r];
    }
    __syncthreads();
    {
      int r = tid >> 6, c = tid & 63;
      float s = 0.f;
#pragma unroll
      for (int w2 = 0; w2 < 8; ++w2) s += part[w2][r][c];
      ubuf[(size_t)(r0+r)*512 + nc0 + c] = s + W2b[nc0 + c];
    }
  }
}

// ---------------------------------------------------------------------------
__global__ __launch_bounds__(256)
void imp_k(const float* __restrict__ part, float* __restrict__ out)
{
  int lane = threadIdx.x & 63, wave = threadIdx.x >> 6;
  float acc = 0.f;
  for (int i = threadIdx.x; i < 576; i += 256) acc += part[i];
#pragma unroll
  for (int off = 32; off; off >>= 1) acc += __shfl_down(acc, off);
  __shared__ float red[4];
  if (lane == 0) red[wave] = acc;
  __syncthreads();
  if (threadIdx.x == 0) out[0] = red[0]+red[1]+red[2]+red[3];
}

// ---------------------------------------------------------------------------
extern "C" void kernel_launch(void* const* d_in, const int* in_sizes, int n_in,
                              void* d_out, int out_size, void* d_ws, size_t ws_size,
                              hipStream_t stream)
{
  (void)in_sizes; (void)n_in; (void)out_size; (void)ws_size;
  const float* image = (const float*)d_in[0];
  const int*   ques  = (const int*)d_in[1];
  const int*   qlen  = (const int*)d_in[2];
  const float* embedW= (const float*)d_in[3];
  const float* Wi_f  = (const float*)d_in[4];
  const float* Wh_f  = (const float*)d_in[5];
  const float* b_f   = (const float*)d_in[6];
  const float* Wi_b  = (const float*)d_in[7];
  const float* Wh_b  = (const float*)d_in[8];
  const float* b_b   = (const float*)d_in[9];
  const float* W1    = (const float*)d_in[10];
  const float* b1    = (const float*)d_in[11];
  const float* W2w   = (const float*)d_in[12];
  const float* W2b   = (const float*)d_in[13];
  const float* W3    = (const float*)d_in[14];
  const float* c0    = (const float*)d_in[15];
  const float* Wmod  = (const float*)d_in[16];
  const float* ic1w  = (const float*)d_in[17];
  const float* ic1b  = (const float*)d_in[18];
  const float* ic2w  = (const float*)d_in[19];
  const float* ic2b  = (const float*)d_in[20];
  const float* i2mw  = (const float*)d_in[21];
  const float* i2mb  = (const float*)d_in[22];
  const float* t2mw  = (const float*)d_in[23];
  const float* t2mb  = (const float*)d_in[24];
  const float* c3ow  = (const float*)d_in[25];
  const float* c3cw  = (const float*)d_in[26];
  const float* c3cb  = (const float*)d_in[27];
  const float* c4ow  = (const float*)d_in[28];
  const float* c4cw  = (const float*)d_in[29];
  const float* c4cb  = (const float*)d_in[30];
  const float* aow   = (const float*)d_in[31];
  const float* ansW  = (const float*)d_in[32];
  const float* ansb  = (const float*)d_in[33];
  const float* o1w   = (const float*)d_in[34];
  const float* o1b   = (const float*)d_in[35];
  const float* o2w   = (const float*)d_in[36];
  const float* o2b   = (const float*)d_in[37];
  float* out = (float*)d_out;
  float* ws  = (float*)d_ws;

  size_t off = 0;
  auto alloc = [&](size_t n){ float* p = ws + off; off += n; return p; };
  short* imgP  = (short*)alloc(600ull*20*64*8/2);
  short* X1p   = (short*)alloc(600ull*16*64*8/2);
  short* X2p   = (short*)alloc(600ull*16*64*8/2);
  short* w1p   = (short*)alloc(20*32*64*8/2);
  short* w2mp  = (short*)alloc(16*32*64*8/2);
  short* w3mp  = (short*)alloc(16*32*64*8/2);
  short* wifp  = (short*)alloc(10*64*64*8/2);
  short* wibp  = (short*)alloc(10*64*64*8/2);
  short* embp  = (short*)alloc(120ull*10*64*8/2);
  unsigned short* imapB = (unsigned short*)alloc(9600ull*512/2);
  unsigned* t2pp = (unsigned*)alloc(512*256);
  float* xWfb  = alloc(64ull*30*1024);
  float* xWbb  = alloc(64ull*30*1024);
  float* lout  = alloc(64ull*30*512);
  float* qbuf  = alloc(64*512);
  float* stck  = alloc(64*150*8);
  float* pvecA = alloc(64*8);
  float* pvecB = alloc(64*8);
  float* memb  = alloc(64*512);
  float* cprev = alloc(64*512);
  float* tmp1a = alloc(9ull*64*512);
  float* ubuf  = alloc(64*512);
  float* wmw   = alloc(64*9);
  float* impp  = alloc(9*64);
  float* swb   = alloc(48);
  float* part67= alloc(64ull*19*2*512);
  float* tmapv = alloc(64*512);
  float* h1b   = alloc(64*1024);
  uint4* whp4  = (uint4*)alloc(2*32*1024*4);

  init_k<<<320, 256, 0, stream>>>(c0, c3ow, c4ow, aow, stck, pvecA, memb, cprev, swb);
  pack4_k<<<256, 256, 0, stream>>>(Wh_f, Wh_b, whp4);
  packB_k<<<160, 256, 0, stream>>>(ic1w, w1p, 20, 32, 640, 512, 1);
  packB_k<<<128, 256, 0, stream>>>(ic2w, w2mp, 16, 32, 512, 512, 1);
  packB_k<<<128, 256, 0, stream>>>(i2mw, w3mp, 16, 32, 512, 512, 1);
  packB_k<<<160, 256, 0, stream>>>(Wi_f, wifp, 10, 64, 300, 1024, 0);
  packB_k<<<160, 256, 0, stream>>>(Wi_b, wibp, 10, 64, 300, 1024, 0);
  packImg_k<<<3000, 256, 0, stream>>>(image, imgP);
  packEmb_k<<<300, 256, 0, stream>>>(embedW, ques, embp);
  packPair_k<<<512, 256, 0, stream>>>(t2mw, t2pp);

  // conv chain (MFMA); conv3 -> bf16 row-major imapB
  gemmM_k<<<dim3(8,150), 256, 0, stream>>>(imgP, w1p,  ic1b, X1p,   20, 32, 512, 1, 1, 16);
  gemmM_k<<<dim3(8,150), 256, 0, stream>>>(X1p,  w2mp, ic2b, X2p,   16, 32, 512, 1, 0, 16);
  gemmM_k<<<dim3(8,150), 256, 0, stream>>>(X2p,  w3mp, i2mb, imapB, 16, 32, 512, 2, 0, 0);
  gemmM_k<<<dim3(16,30), 256, 0, stream>>>(embp, wifp, b_f, xWfb, 10, 64, 1024, 0, 0, 0);
  gemmM_k<<<dim3(16,30), 256, 0, stream>>>(embp, wibp, b_b, xWbb, 10, 64, 1024, 0, 0, 0);

  lstm4_k<<<128, 1024, 0, stream>>>(xWfb, xWbb, whp4, qlen, lout, qbuf);

  // tmp1all[t] = q @ W1[t] + b1 (all 9 t)
  gemm64b_k<<<dim3(8,8,9), 512, 0, stream>>>(
      qbuf, 0, 9, (const float*)nullptr, 0,
      W1, 262144, b1, 0, tmp1a, 32768, 512, 0);
  // u for t=0
  gemm64b_k<<<dim3(8,8,1), 512, 0, stream>>>(
      tmp1a, 0, 9, cprev, 512, W2w, 0, W2b, 0, ubuf, 0, 512, 0);

  for (int t = 0; t < 9; ++t) {
    float* pvIn  = (t & 1) ? pvecB : pvecA;
    float* pvOut = (t & 1) ? pvecA : pvecB;
    kcattn2_k<<<64, 256, 0, stream>>>(ubuf, Wmod, lout, W3, t2pp, t2mb,
                                      wmw, impp, cprev, tmapv, t);
    modules2_k<<<dim3(64,19), 256, 0, stream>>>(
        imapB, tmapv, stck, pvIn, pvOut, swb, c3cw, c3cb, c4cw, c4cb, wmw,
        part67);
    ansu_k<<<dim3(8,8), 512, 0, stream>>>(
        part67, tmapv, ansW, ansb, wmw, memb,
        tmp1a + (size_t)(t < 8 ? t+1 : 0)*32768, cprev, W2w, W2b, ubuf,
        (t < 8) ? 1 : 0);
  }

  // h1 = elu([q, mem] @ out1 + b);  logits = h1 @ out2 + b
  gemm64b_k<<<dim3(16,8,1), 512, 0, stream>>>(
      qbuf, 0, 9, memb, 512, o1w, 0, o1b, 0, h1b, 0, 1024, 1);
  gemm64b_k<<<dim3(1,8,1), 512, 0, stream>>>(
      h1b, 0, 10, (const float*)nullptr, 0, o2w, 0, o2b, 0, out, 0, 32, 0);
  imp_k<<<1, 256, 0, stream>>>(impp, out + 2048);
}

// Round 8
// 1158.146 us; speedup vs baseline: 1.1549x; 1.1549x over previous
//
#include <hip/hip_runtime.h>
#include <math.h>

#define DEV __device__ __forceinline__

DEV float fexp(float x){ return __expf(x); }
DEV float elu_(float x){ return x > 0.f ? x : fexp(x) - 1.f; }
DEV float sigm_(float x){ return 1.f/(1.f + fexp(-x)); }
DEV float tanh_(float x){ float e = fexp(2.f*x); return 1.f - 2.f/(e + 1.f); }
DEV unsigned bf16r(float x){ unsigned u = __float_as_uint(x);
  return (u + 0x7fffu + ((u>>16)&1u)) >> 16; }
DEV float blo(unsigned u){ return __uint_as_float(u << 16); }
DEV float bhi(unsigned u){ return __uint_as_float(u & 0xffff0000u); }
DEV float bl(unsigned short u){ return __uint_as_float(((unsigned)u) << 16); }

using frag  = __attribute__((ext_vector_type(8))) short;   // 8 bf16 (4 VGPRs)
using f32x4 = __attribute__((ext_vector_type(4))) float;   // MFMA acc

// ---------------------------------------------------------------------------
// device pack helpers (indexed by flat element id)
// ---------------------------------------------------------------------------
DEV void d_pack4(const float* __restrict__ Whf, const float* __restrict__ Whb,
                 uint4* __restrict__ whp4, int idx)
{
  int dir = idx >> 15;
  int rem = idx & 32767;
  int kg  = rem >> 10;
  int n   = rem & 1023;
  const float* Wh = dir ? Whb : Whf;
  unsigned v[4];
#pragma unroll
  for (int j = 0; j < 4; ++j) {
    int k = kg*8 + 2*j;
    float lo = Wh[(size_t)k*1024 + n];
    float hi = Wh[(size_t)(k+1)*1024 + n];
    v[j] = bf16r(lo) | (bf16r(hi) << 16);
  }
  whp4[idx] = make_uint4(v[0], v[1], v[2], v[3]);
}

DEV void d_packB(const float* __restrict__ W, short* __restrict__ Bp,
                 int KC, int Ng, int Ksrc, int N, int trans, int idx)
{
  if (idx >= KC*Ng*64) return;
  int lane = idx & 63;
  int g    = (idx >> 6) % Ng;
  int kc   = idx / (64*Ng);
  int n = g*16 + (lane & 15);
  int kb = kc*32 + ((lane >> 4) << 3);
  unsigned o[4];
#pragma unroll
  for (int jj = 0; jj < 4; ++jj) {
    int k0 = kb + 2*jj;
    float v0 = (k0   < Ksrc) ? (trans ? W[(size_t)n*Ksrc + k0]   : W[(size_t)(k0)*N + n])   : 0.f;
    float v1 = (k0+1 < Ksrc) ? (trans ? W[(size_t)n*Ksrc + k0+1] : W[(size_t)(k0+1)*N + n]) : 0.f;
    o[jj] = bf16r(v0) | (bf16r(v1) << 16);
  }
  *(uint4*)(Bp + (size_t)idx*8) = make_uint4(o[0], o[1], o[2], o[3]);
}

DEV void d_packImg(const float* __restrict__ image, short* __restrict__ Ap, int idx)
{
  int lane = idx & 63;
  int kc   = (idx >> 6) % 20;
  int mt   = idx / 1280;
  int row = mt*16 + (lane & 15);
  int b = row / 150, p = row % 150;
  int cb = kc*32 + ((lane >> 4) << 3);
  unsigned o[4];
#pragma unroll
  for (int jj = 0; jj < 4; ++jj) {
    float v0 = image[((size_t)b*640 + cb + 2*jj    )*150 + p];
    float v1 = image[((size_t)b*640 + cb + 2*jj + 1)*150 + p];
    o[jj] = bf16r(v0) | (bf16r(v1) << 16);
  }
  *(uint4*)(Ap + (size_t)idx*8) = make_uint4(o[0], o[1], o[2], o[3]);
}

DEV void d_packEmb(const float* __restrict__ embedW, const int* __restrict__ ques,
                   short* __restrict__ Ap, int idx)
{
  int lane = idx & 63;
  int kc   = (idx >> 6) % 10;
  int mt   = idx / 640;
  int row = mt*16 + (lane & 15);
  int q = ques[row];
  int kb = kc*32 + ((lane >> 4) << 3);
  unsigned o[4];
#pragma unroll
  for (int jj = 0; jj < 4; ++jj) {
    int k0 = kb + 2*jj;
    float v0 = (k0   < 300) ? embedW[(size_t)q*300 + k0]   : 0.f;
    float v1 = (k0+1 < 300) ? embedW[(size_t)q*300 + k0+1] : 0.f;
    o[jj] = bf16r(v0) | (bf16r(v1) << 16);
  }
  *(uint4*)(Ap + (size_t)idx*8) = make_uint4(o[0], o[1], o[2], o[3]);
}

// ---------------------------------------------------------------------------
// ONE dispatch for all independent pre-stage work:
// [0,320)   init: stack/pvec/mem/cprev/swb/pl
// [320,576) pack4 (Wh)          [576,736)  packB ic1w    [736,864)  packB ic2w
// [864,992) packB i2mw          [992,1152) packB Wi_f    [1152,1312) packB Wi_b
// [1312,4312) packImg           [4312,4612) packEmb      [4612,5124) packPair t2m
// ---------------------------------------------------------------------------
__global__ __launch_bounds__(256)
void megapack_k(const float* __restrict__ c0, const float* __restrict__ c3ow,
                const float* __restrict__ c4ow, const float* __restrict__ aow,
                float* __restrict__ stack, float* __restrict__ pvecA,
                float* __restrict__ mem, float* __restrict__ cprev,
                float* __restrict__ swb, float* __restrict__ pl,
                const float* __restrict__ Whf, const float* __restrict__ Whb,
                uint4* __restrict__ whp4,
                const float* __restrict__ ic1w, short* __restrict__ w1p,
                const float* __restrict__ ic2w, short* __restrict__ w2mp,
                const float* __restrict__ i2mw, short* __restrict__ w3mp,
                const float* __restrict__ Wif, short* __restrict__ wifp,
                const float* __restrict__ Wib, short* __restrict__ wibp,
                const float* __restrict__ image, short* __restrict__ imgP,
                const float* __restrict__ embedW, const int* __restrict__ ques,
                short* __restrict__ embp,
                const float* __restrict__ t2mw, unsigned* __restrict__ t2pp)
{
  const int bx = blockIdx.x, tid = threadIdx.x;
  if (bx < 320) {
    int idx = bx*256 + tid;
    int stride = 320*256;
    for (int i = idx; i < 64*150*8; i += stride) stack[i] = 0.f;
    for (int i = idx; i < 64*8;    i += stride) pvecA[i] = ((i & 7) == 0) ? 1.f : 0.f;
    for (int i = idx; i < 64*512;  i += stride) mem[i] = 0.f;
    for (int i = idx; i < 64*512;  i += stride) cprev[i] = c0[i & 511];
    for (int i = idx; i < 9*2*64*512; i += stride) pl[i] = 0.f;
    if (idx < 8) {
      const float* ow = (idx < 4) ? (c3ow + idx*6)
                      : (idx < 6) ? (c4ow + (idx-4)*6)
                                  : (aow  + (idx-6)*6);
      float mx = ow[0];
      for (int m = 1; m < 6; ++m) mx = fmaxf(mx, ow[m]);
      float e[6]; float s = 0.f;
      for (int m = 0; m < 6; ++m) { e[m] = fexp(ow[m]-mx); s += e[m]; }
      for (int m = 0; m < 6; ++m) swb[idx*6+m] = e[m]/s;
    }
  } else if (bx < 576) {
    d_pack4(Whf, Whb, whp4, (bx-320)*256 + tid);
  } else if (bx < 736) {
    d_packB(ic1w, w1p, 20, 32, 640, 512, 1, (bx-576)*256 + tid);
  } else if (bx < 864) {
    d_packB(ic2w, w2mp, 16, 32, 512, 512, 1, (bx-736)*256 + tid);
  } else if (bx < 992) {
    d_packB(i2mw, w3mp, 16, 32, 512, 512, 1, (bx-864)*256 + tid);
  } else if (bx < 1152) {
    d_packB(Wif, wifp, 10, 64, 300, 1024, 0, (bx-992)*256 + tid);
  } else if (bx < 1312) {
    d_packB(Wib, wibp, 10, 64, 300, 1024, 0, (bx-1152)*256 + tid);
  } else if (bx < 4312) {
    d_packImg(image, imgP, (bx-1312)*256 + tid);
  } else if (bx < 4612) {
    d_packEmb(embedW, ques, embp, (bx-4312)*256 + tid);
  } else {
    int idx = (bx-4612)*256 + tid;   // 512*256
    int k = idx >> 8, c = idx & 255;
    t2pp[idx] = bf16r(t2mw[(size_t)k*512 + c]) | (bf16r(t2mw[(size_t)k*512 + 256 + c]) << 16);
  }
}

// ---------------------------------------------------------------------------
// MFMA GEMM, dual problem sets selected by blockIdx.z (pass same twice for z=1).
// mode 0: fp32 row-major; mode 1: bf16 A-pack; mode 2: bf16 row-major
// ---------------------------------------------------------------------------
__global__ __launch_bounds__(256)
void gemmM_k(const short* __restrict__ ApA, const short* __restrict__ ApB,
             const short* __restrict__ BpA, const short* __restrict__ BpB,
             const float* __restrict__ biasA, const float* __restrict__ biasB,
             void* __restrict__ CoutA, void* __restrict__ CoutB,
             int KC, int Ng, int N, int mode, int act, int KCout)
{
  __shared__ float lds[4][16][68];
  const int z = blockIdx.z;
  const short* Ap = z ? ApB : ApA;
  const short* Bp = z ? BpB : BpA;
  const float* bias = z ? biasB : biasA;
  void* Cout = z ? CoutB : CoutA;
  const int tid = threadIdx.x, lane = tid & 63, w = tid >> 6;
  const int mt = blockIdx.y*4 + w;
  const int ncol0 = blockIdx.x*64;
  const short* Abase = Ap + (((size_t)mt*KC) << 9) + lane*8;
  const short* Bbase = Bp + (((size_t)blockIdx.x*4) << 9) + lane*8;
  f32x4 acc0 = {0.f,0.f,0.f,0.f}, acc1 = acc0, acc2 = acc0, acc3 = acc0;
#pragma unroll 2
  for (int kc = 0; kc < KC; ++kc) {
    frag a = *(const frag*)(Abase + ((size_t)kc << 9));
    const short* bk = Bbase + (((size_t)kc*Ng) << 9);
    frag b0 = *(const frag*)(bk);
    frag b1 = *(const frag*)(bk + 512);
    frag b2 = *(const frag*)(bk + 1024);
    frag b3 = *(const frag*)(bk + 1536);
    acc0 = __builtin_amdgcn_mfma_f32_16x16x32_bf16(a, b0, acc0, 0, 0, 0);
    acc1 = __builtin_amdgcn_mfma_f32_16x16x32_bf16(a, b1, acc1, 0, 0, 0);
    acc2 = __builtin_amdgcn_mfma_f32_16x16x32_bf16(a, b2, acc2, 0, 0, 0);
    acc3 = __builtin_amdgcn_mfma_f32_16x16x32_bf16(a, b3, acc3, 0, 0, 0);
  }
  {
    int colb = lane & 15, rowb = (lane >> 4)*4;
#pragma unroll
    for (int r = 0; r < 4; ++r) {
      lds[w][rowb+r][ 0+colb] = acc0[r];
      lds[w][rowb+r][16+colb] = acc1[r];
      lds[w][rowb+r][32+colb] = acc2[r];
      lds[w][rowb+r][48+colb] = acc3[r];
    }
  }
  __syncthreads();
  if (mode == 0) {
    float* C = (float*)Cout;
    int mloc = lane >> 2, q4 = lane & 3;
    size_t rowoff = (size_t)(mt*16 + mloc)*N + ncol0 + q4*16;
#pragma unroll
    for (int i = 0; i < 4; ++i) {
      float4 v = *(float4*)&lds[w][mloc][q4*16 + i*4];
      const float* bp = bias + ncol0 + q4*16 + i*4;
      v.x += bp[0]; v.y += bp[1]; v.z += bp[2]; v.w += bp[3];
      if (act) { v.x = elu_(v.x); v.y = elu_(v.y); v.z = elu_(v.z); v.w = elu_(v.w); }
      *(float4*)&C[rowoff + i*4] = v;
    }
  } else if (mode == 1) {
    short* C = (short*)Cout;
    int m = lane & 15, qb = (lane >> 4)*8;
#pragma unroll
    for (int h = 0; h < 2; ++h) {
      int nl = h*32 + qb;
      unsigned o[4];
#pragma unroll
      for (int jj = 0; jj < 4; ++jj) {
        float v0 = lds[w][m][nl + 2*jj]     + bias[ncol0 + nl + 2*jj];
        float v1 = lds[w][m][nl + 2*jj + 1] + bias[ncol0 + nl + 2*jj + 1];
        if (act) { v0 = elu_(v0); v1 = elu_(v1); }
        o[jj] = bf16r(v0) | (bf16r(v1) << 16);
      }
      *(uint4*)(C + (((size_t)mt*KCout + (ncol0 >> 5) + h) << 9) + lane*8)
          = make_uint4(o[0], o[1], o[2], o[3]);
    }
  } else {
    unsigned short* C = (unsigned short*)Cout;
    int row = lane >> 2, cb = (lane & 3)*16;
#pragma unroll
    for (int h = 0; h < 2; ++h) {
      unsigned o[4];
#pragma unroll
      for (int jj = 0; jj < 4; ++jj) {
        float v0 = lds[w][row][cb + h*8 + 2*jj]     + bias[ncol0 + cb + h*8 + 2*jj];
        float v1 = lds[w][row][cb + h*8 + 2*jj + 1] + bias[ncol0 + cb + h*8 + 2*jj + 1];
        if (act) { v0 = elu_(v0); v1 = elu_(v1); }
        o[jj] = bf16r(v0) | (bf16r(v1) << 16);
      }
      *(uint4*)&C[(size_t)(mt*16 + row)*N + ncol0 + cb + h*8]
          = make_uint4(o[0], o[1], o[2], o[3]);
    }
  }
}

// ---------------------------------------------------------------------------
// 64-row batch GEMM, K-split across waves (latency-optimized)
// ---------------------------------------------------------------------------
__global__ __launch_bounds__(512)
void gemm64b_k(const float* __restrict__ A1, long zA1, int K1log,
               const float* __restrict__ A2, int K2,
               const float* __restrict__ B, long zB,
               const float* __restrict__ bias, int zbias,
               float* __restrict__ C, long zC, int N, int act)
{
  const int K1 = 1 << K1log;
  const int Kt = K1 + K2;
  __shared__ __align__(16) float As[8][1024];
  __shared__ float part[8][8][64];
  const int tid = threadIdx.x;
  const int z = blockIdx.z;
  const int r0 = blockIdx.y*8;
  {
    const float* a1 = A1 + (size_t)z*zA1;
    const int nf4 = (8*K1) >> 2;
    for (int e4 = tid; e4 < nf4; e4 += 512) {
      int r = e4 >> (K1log-2);
      int k4 = (e4 & ((K1>>2)-1)) << 2;
      *(float4*)&As[r][k4] = *(const float4*)&a1[(size_t)(r0+r)*K1 + k4];
    }
    if (K2 > 0) {
      for (int e4 = tid; e4 < 1024; e4 += 512) {
        int r = e4 >> 7;
        int k4 = (e4 & 127) << 2;
        *(float4*)&As[r][K1+k4] = *(const float4*)&A2[(size_t)(r0+r)*512 + k4];
      }
    }
  }
  __syncthreads();
  const int lane = tid & 63, w = tid >> 6;
  const int n = blockIdx.x*64 + lane;
  const bool nv = n < N;
  const int kseg = Kt >> 3;
  const int k0 = w*kseg;
  const float* Bp = B + (size_t)z*zB + (size_t)k0*N + (nv ? n : 0);
  float acc[8] = {0,0,0,0,0,0,0,0};
#pragma unroll 8
  for (int kk = 0; kk < kseg; ++kk) {
    float bv = nv ? Bp[(size_t)kk*N] : 0.f;
    int k = k0 + kk;
#pragma unroll
    for (int r = 0; r < 8; ++r) acc[r] += As[r][k]*bv;
  }
#pragma unroll
  for (int r = 0; r < 8; ++r) part[w][r][lane] = acc[r];
  __syncthreads();
  {
    int r = tid >> 6, c = tid & 63;
    int nn = blockIdx.x*64 + c;
    if (nn < N) {
      float s = 0.f;
#pragma unroll
      for (int w2 = 0; w2 < 8; ++w2) s += part[w2][r][c];
      s += bias ? bias[(size_t)z*zbias + nn] : 0.f;
      if (act == 1) s = elu_(s);
      C[(size_t)z*zC + (size_t)(r0+r)*N + nn] = s;
    }
  }
}

// ---------------------------------------------------------------------------
// bidirectional masked LSTM; 128 blocks = (dir, batch); Wh as uint4 bf16-pairs
// ---------------------------------------------------------------------------
__global__ __launch_bounds__(1024)
void lstm4_k(const float* __restrict__ xWf, const float* __restrict__ xWb,
             const uint4* __restrict__ whp4,
             const int* __restrict__ qlen, float* __restrict__ lstm_out,
             float* __restrict__ qout)
{
  int dir = blockIdx.x >> 6;
  int b   = blockIdx.x & 63;
  const float* xW = dir ? xWb : xWf;
  const uint4* Wp = whp4 + (size_t)dir*32768 + threadIdx.x;
  __shared__ __align__(16) float hl[256];
  __shared__ __align__(16) float cl[256];
  __shared__ float zl[1024];
  int tid = threadIdx.x;
  if (tid < 256) { hl[tid] = 0.f; cl[tid] = 0.f; }
  int len = qlen[b];
  for (int ss = 0; ss < 30; ++ss) {
    int s = dir ? (29-ss) : ss;
    __syncthreads();
    float z = xW[((size_t)b*30 + s)*1024 + tid];
#pragma unroll 4
    for (int kg = 0; kg < 32; ++kg) {
      uint4 w = Wp[(size_t)kg*1024];
      float4 ha = *(const float4*)&hl[kg*8];
      float4 hb = *(const float4*)&hl[kg*8+4];
      z += ha.x*blo(w.x) + ha.y*bhi(w.x) + ha.z*blo(w.y) + ha.w*bhi(w.y)
         + hb.x*blo(w.z) + hb.y*bhi(w.z) + hb.z*blo(w.w) + hb.w*bhi(w.w);
    }
    zl[tid] = z;
    __syncthreads();
    if (tid < 256) {
      float iv = zl[tid], fv = zl[256+tid], gv = zl[512+tid], ov = zl[768+tid];
      float cn = sigm_(fv)*cl[tid] + sigm_(iv)*tanh_(gv);
      float hn = sigm_(ov)*tanh_(cn);
      bool m = s < len;
      lstm_out[((size_t)b*30 + s)*512 + dir*256 + tid] = m ? hn : 0.f;
      if (m) { hl[tid] = hn; cl[tid] = cn; }
    }
  }
  __syncthreads();
  if (tid < 256) qout[(size_t)b*512 + dir*256 + tid] = hl[tid];
}

// ---------------------------------------------------------------------------
// fused kc + attn + tmap
// ---------------------------------------------------------------------------
__global__ __launch_bounds__(256)
void kcattn2_k(const float* __restrict__ u, const float* __restrict__ Wmod,
               const float* __restrict__ lstm_out, const float* __restrict__ W3,
               const unsigned* __restrict__ t2pp, const float* __restrict__ t2mb,
               float* __restrict__ wout, float* __restrict__ imp_part,
               float* __restrict__ cout, float* __restrict__ tmapv, int t)
{
  int b = blockIdx.x;
  int lane = threadIdx.x & 63, wave = threadIdx.x >> 6;
  __shared__ float ush[512];
  __shared__ float sC[512];
  __shared__ float wl[9];
  __shared__ float sc[32], at[32];
  ush[threadIdx.x]     = u[b*512 + threadIdx.x];
  ush[256+threadIdx.x] = u[b*512 + 256 + threadIdx.x];
  __syncthreads();
  for (int m = wave; m < 9; m += 4) {
    float acc = 0.f;
    for (int k = lane; k < 512; k += 64) acc += ush[k]*Wmod[k*9+m];
#pragma unroll
    for (int off = 32; off; off >>= 1) acc += __shfl_down(acc, off);
    if (lane == 0) wl[m] = acc;
  }
  for (int s = wave; s < 30; s += 4) {
    float acc = 0.f;
    const float* lo = lstm_out + ((size_t)b*30 + s)*512;
    for (int h = lane; h < 512; h += 64) acc += lo[h]*ush[h]*W3[h];
#pragma unroll
    for (int off = 32; off; off >>= 1) acc += __shfl_down(acc, off);
    if (lane == 0) sc[s] = acc;
  }
  __syncthreads();
  if (threadIdx.x == 0) {
    float mx = wl[0];
    for (int m = 1; m < 9; ++m) mx = fmaxf(mx, wl[m]);
    float s = 0.f;
    for (int m = 0; m < 9; ++m) s += fexp(wl[m]-mx);
    float ls = logf(s);
    float ent = 0.f;
    for (int m = 0; m < 9; ++m) {
      float l = wl[m]-mx-ls;
      float w = fexp(l);
      wout[b*9+m] = w;
      ent -= w*l;
    }
    imp_part[t*64+b] = ent;
  }
  if (wave == 1) {
    float v = (lane < 30) ? sc[lane] : -3.4e38f;
    float mx = v;
#pragma unroll
    for (int off = 32; off; off >>= 1) mx = fmaxf(mx, __shfl_xor(mx, off));
    float e = (lane < 30) ? fexp(v-mx) : 0.f;
    float ssum = e;
#pragma unroll
    for (int off = 32; off; off >>= 1) ssum += __shfl_xor(ssum, off);
    if (lane < 30) at[lane] = e/ssum;
  }
  __syncthreads();
  for (int h = threadIdx.x; h < 512; h += 256) {
    float acc = 0.f;
#pragma unroll 6
    for (int s = 0; s < 30; ++s) acc += at[s]*lstm_out[((size_t)b*30 + s)*512 + h];
    cout[b*512+h] = acc;
    sC[h] = acc;
  }
  __syncthreads();
  {
    float a0 = 0.f, a1 = 0.f;
    const unsigned* tp = t2pp + threadIdx.x;
#pragma unroll 8
    for (int k = 0; k < 512; ++k) {
      float cv = sC[k];
      unsigned wv2 = tp[(size_t)k*256];
      a0 += cv*blo(wv2);
      a1 += cv*bhi(wv2);
    }
    tmapv[b*512 + threadIdx.x]       = a0 + t2mb[threadIdx.x];
    tmapv[b*512 + 256 + threadIdx.x] = a1 + t2mb[256 + threadIdx.x];
  }
}

// ---------------------------------------------------------------------------
// fused modules + pooled partials (atomicAdd into per-t pl buffer) + stack
// update + pvec ping-pong.  grid (64 b, 19 pb).
// ---------------------------------------------------------------------------
__global__ __launch_bounds__(256)
void modules2_k(const unsigned short* __restrict__ imapB, const float* __restrict__ tmapv,
                float* __restrict__ stack, const float* __restrict__ pvecIn,
                float* __restrict__ pvecOut,
                const float* __restrict__ swb, const float* __restrict__ c3w,
                const float* __restrict__ c3b, const float* __restrict__ c4w,
                const float* __restrict__ c4b, const float* __restrict__ wmod,
                float* __restrict__ plt)
{
  int b  = blockIdx.x;
  int pb = blockIdx.y;
  int lane = threadIdx.x & 63, wave = threadIdx.x >> 6;
  __shared__ float sT[512];
  __shared__ float pv[8], pd[8], wm[9];
  __shared__ float wpart[4][2][512];
  for (int j = threadIdx.x; j < 512; j += 256) sT[j] = tmapv[b*512 + j];
  if (threadIdx.x < 8) pv[threadIdx.x] = pvecIn[b*8+threadIdx.x];
  if (threadIdx.x >= 64 && threadIdx.x < 73) wm[threadIdx.x-64] = wmod[b*9 + threadIdx.x-64];
  __syncthreads();
  if (threadIdx.x < 8) {
    int l = threadIdx.x;
    pd[l] = (l < 7 ? pv[l+1] : 0.f) + (l == 0 ? pv[0] : 0.f);
  }
  __syncthreads();
  if (pb == 0 && threadIdx.x < 8) {
    int l = threadIdx.x;
    float WP = wm[0]+wm[1]+wm[2]+wm[3] + wm[6] + wm[8];
    float WD = wm[4]+wm[5] + wm[7];
    pvecOut[b*8+l] = WP*pv[l] + WD*pd[l];
  }

  float W[8][6];
#pragma unroll
  for (int m = 0; m < 8; ++m)
#pragma unroll
    for (int i = 0; i < 6; ++i) W[m][i] = swb[m*6+i];
  float W03 = wm[0]+wm[1]+wm[2]+wm[3];
  float W45 = wm[4]+wm[5];

  float acc6[8], acc7[8];
#pragma unroll
  for (int i = 0; i < 8; ++i) { acc6[i] = 0.f; acc7[i] = 0.f; }

  for (int pi = 0; pi < 2; ++pi) {
    int p = pb*8 + wave*2 + pi;
    if (p < 150) {
      const float* st = stack + ((size_t)b*150 + p)*8;
      float a = 0.f, av2 = 0.f;
#pragma unroll
      for (int l = 0; l < 8; ++l) { float v = st[l]; a += v*pv[l]; av2 += v*pd[l]; }
      float part[6] = {0,0,0,0,0,0};
#pragma unroll 2
      for (int i = 0; i < 8; ++i) {
        int d = i*64 + lane;
        float x = bl(imapB[((size_t)b*150 + p)*512 + d]);
        float t = sT[d];
#pragma unroll
        for (int m = 0; m < 4; ++m) {
          float c1 = W[m][0]*t + W[m][1] + W[m][4] + (W[m][2] + W[m][3]*t)*a;
          float c0 = W[m][1]*t + W[m][5]*t*a;
          part[m] += elu_(c1*x + c0) * c3w[m*512+d];
        }
#pragma unroll
        for (int m = 0; m < 2; ++m) {
          float c1 = W[4+m][0]*t + W[4+m][1] + W[4+m][2]*a + W[4+m][3]*av2
                   + W[4+m][4]*a*av2 + W[4+m][5]*t*(a+av2);
          part[4+m] += elu_(c1*x + W[4+m][1]*t) * c4w[m*512+d];
        }
        float c16 = W[6][0]*t + W[6][1] + W[6][4] + (W[6][2] + W[6][3]*t)*a;
        float c06 = W[6][1]*t + W[6][5]*t*a;
        acc6[i] += elu_(c16*x + c06);
        float c17 = W[7][0]*t + W[7][1] + W[7][2]*a + W[7][3]*av2
                  + W[7][4]*a*av2 + W[7][5]*t*(a+av2);
        acc7[i] += elu_(c17*x + W[7][1]*t);
      }
#pragma unroll
      for (int m = 0; m < 6; ++m) {
#pragma unroll
        for (int off = 32; off; off >>= 1) part[m] += __shfl_down(part[m], off);
        part[m] = __shfl(part[m], 0);
      }
      float r3  = wm[0]*(part[0]+c3b[0]) + wm[1]*(part[1]+c3b[1])
                + wm[2]*(part[2]+c3b[2]) + wm[3]*(part[3]+c3b[3]);
      float r45 = wm[4]*(part[4]+c4b[0]) + wm[5]*(part[5]+c4b[1]);
      if (lane < 8) {
        int l = lane;
        size_t idx = ((size_t)b*150 + p)*8 + l;
        stack[idx] = stack[idx]*(1.f - W03*pv[l] - W45*pd[l])
                   + pv[l]*r3 + pd[l]*r45;
      }
    }
  }
#pragma unroll
  for (int i = 0; i < 8; ++i) {
    wpart[wave][0][i*64+lane] = acc6[i];
    wpart[wave][1][i*64+lane] = acc7[i];
  }
  __syncthreads();
  for (int e = threadIdx.x; e < 1024; e += 256) {
    int which = e >> 9, d = e & 511;
    float s = wpart[0][which][d] + wpart[1][which][d]
            + wpart[2][which][d] + wpart[3][which][d];
    atomicAdd(&plt[(size_t)which*32768 + b*512 + d], s * (1.f/150.f));
  }
}

// ---------------------------------------------------------------------------
// fused ans GEMMs (z=0,1) + mem blend + next-t u GEMM.  grid (8,8), 512 thr.
// ---------------------------------------------------------------------------
__global__ __launch_bounds__(512)
void ansu_k(const float* __restrict__ plt, const float* __restrict__ tmapv,
            const float* __restrict__ ansW, const float* __restrict__ ansb,
            const float* __restrict__ wmw, float* __restrict__ memb,
            const float* __restrict__ tmp1n, const float* __restrict__ cprev,
            const float* __restrict__ W2w, const float* __restrict__ W2b,
            float* __restrict__ ubuf, int do_u)
{
  __shared__ __align__(16) float As[8][1024];
  __shared__ float part[8][8][64];
  __shared__ float m6s[8][64];
  const int tid = threadIdx.x;
  const int r0 = blockIdx.y*8;
  const int nc0 = blockIdx.x*64;
  const int lane = tid & 63, w = tid >> 6;

  for (int z = 0; z < 2; ++z) {
    for (int e4 = tid; e4 < 1024; e4 += 512) {
      int r = e4 >> 7, k4 = (e4 & 127) << 2;
      *(float4*)&As[r][k4]     = *(const float4*)&plt[(size_t)z*32768 + (size_t)(r0+r)*512 + k4];
      *(float4*)&As[r][512+k4] = *(const float4*)&tmapv[(size_t)(r0+r)*512 + k4];
    }
    __syncthreads();
    {
      const float* Bp = ansW + (size_t)z*524288 + (size_t)(w*128)*512 + nc0 + lane;
      float acc[8] = {0,0,0,0,0,0,0,0};
      int k0 = w*128;
#pragma unroll 8
      for (int kk = 0; kk < 128; ++kk) {
        float bv = Bp[(size_t)kk*512];
#pragma unroll
        for (int r = 0; r < 8; ++r) acc[r] += As[r][k0+kk]*bv;
      }
#pragma unroll
      for (int r = 0; r < 8; ++r) part[w][r][lane] = acc[r];
    }
    __syncthreads();
    {
      int r = tid >> 6, c = tid & 63;
      float s = 0.f;
#pragma unroll
      for (int w2 = 0; w2 < 8; ++w2) s += part[w2][r][c];
      s += ansb[z*512 + nc0 + c];
      if (z == 0) {
        m6s[r][c] = s;
      } else {
        int b = r0 + r;
        float w6 = wmw[b*9+6], w7 = wmw[b*9+7];
        memb[(size_t)b*512 + nc0 + c] = w6*m6s[r][c] + w7*s
                                      + (1.f - w6 - w7)*memb[(size_t)b*512 + nc0 + c];
      }
    }
    __syncthreads();
  }

  if (do_u) {
    for (int e4 = tid; e4 < 1024; e4 += 512) {
      int r = e4 >> 7, k4 = (e4 & 127) << 2;
      *(float4*)&As[r][k4]     = *(const float4*)&tmp1n[(size_t)(r0+r)*512 + k4];
      *(float4*)&As[r][512+k4] = *(const float4*)&cprev[(size_t)(r0+r)*512 + k4];
    }
    __syncthreads();
    {
      const float* Bp = W2w + (size_t)(w*128)*512 + nc0 + lane;
      float acc[8] = {0,0,0,0,0,0,0,0};
      int k0 = w*128;
#pragma unroll 8
      for (int kk = 0; kk < 128; ++kk) {
        float bv = Bp[(size_t)kk*512];
#pragma unroll
        for (int r = 0; r < 8; ++r) acc[r] += As[r][k0+kk]*bv;
      }
#pragma unroll
      for (int r = 0; r < 8; ++r) part[w][r][lane] = acc[r];
    }
    __syncthreads();
    {
      int r = tid >> 6, c = tid & 63;
      float s = 0.f;
#pragma unroll
      for (int w2 = 0; w2 < 8; ++w2) s += part[w2][r][c];
      ubuf[(size_t)(r0+r)*512 + nc0 + c] = s + W2b[nc0 + c];
    }
  }
}

// ---------------------------------------------------------------------------
__global__ __launch_bounds__(256)
void imp_k(const float* __restrict__ part, float* __restrict__ out)
{
  int lane = threadIdx.x & 63, wave = threadIdx.x >> 6;
  float acc = 0.f;
  for (int i = threadIdx.x; i < 576; i += 256) acc += part[i];
#pragma unroll
  for (int off = 32; off; off >>= 1) acc += __shfl_down(acc, off);
  __shared__ float red[4];
  if (lane == 0) red[wave] = acc;
  __syncthreads();
  if (threadIdx.x == 0) out[0] = red[0]+red[1]+red[2]+red[3];
}

// ---------------------------------------------------------------------------
extern "C" void kernel_launch(void* const* d_in, const int* in_sizes, int n_in,
                              void* d_out, int out_size, void* d_ws, size_t ws_size,
                              hipStream_t stream)
{
  (void)in_sizes; (void)n_in; (void)out_size; (void)ws_size;
  const float* image = (const float*)d_in[0];
  const int*   ques  = (const int*)d_in[1];
  const int*   qlen  = (const int*)d_in[2];
  const float* embedW= (const float*)d_in[3];
  const float* Wi_f  = (const float*)d_in[4];
  const float* Wh_f  = (const float*)d_in[5];
  const float* b_f   = (const float*)d_in[6];
  const float* Wi_b  = (const float*)d_in[7];
  const float* Wh_b  = (const float*)d_in[8];
  const float* b_b   = (const float*)d_in[9];
  const float* W1    = (const float*)d_in[10];
  const float* b1    = (const float*)d_in[11];
  const float* W2w   = (const float*)d_in[12];
  const float* W2b   = (const float*)d_in[13];
  const float* W3    = (const float*)d_in[14];
  const float* c0    = (const float*)d_in[15];
  const float* Wmod  = (const float*)d_in[16];
  const float* ic1w  = (const float*)d_in[17];
  const float* ic1b  = (const float*)d_in[18];
  const float* ic2w  = (const float*)d_in[19];
  const float* ic2b  = (const float*)d_in[20];
  const float* i2mw  = (const float*)d_in[21];
  const float* i2mb  = (const float*)d_in[22];
  const float* t2mw  = (const float*)d_in[23];
  const float* t2mb  = (const float*)d_in[24];
  const float* c3ow  = (const float*)d_in[25];
  const float* c3cw  = (const float*)d_in[26];
  const float* c3cb  = (const float*)d_in[27];
  const float* c4ow  = (const float*)d_in[28];
  const float* c4cw  = (const float*)d_in[29];
  const float* c4cb  = (const float*)d_in[30];
  const float* aow   = (const float*)d_in[31];
  const float* ansW  = (const float*)d_in[32];
  const float* ansb  = (const float*)d_in[33];
  const float* o1w   = (const float*)d_in[34];
  const float* o1b   = (const float*)d_in[35];
  const float* o2w   = (const float*)d_in[36];
  const float* o2b   = (const float*)d_in[37];
  float* out = (float*)d_out;
  float* ws  = (float*)d_ws;

  size_t off = 0;
  auto alloc = [&](size_t n){ float* p = ws + off; off += n; return p; };
  short* imgP  = (short*)alloc(600ull*20*64*8/2);
  short* X1p   = (short*)alloc(600ull*16*64*8/2);
  short* X2p   = (short*)alloc(600ull*16*64*8/2);
  short* w1p   = (short*)alloc(20*32*64*8/2);
  short* w2mp  = (short*)alloc(16*32*64*8/2);
  short* w3mp  = (short*)alloc(16*32*64*8/2);
  short* wifp  = (short*)alloc(10*64*64*8/2);
  short* wibp  = (short*)alloc(10*64*64*8/2);
  short* embp  = (short*)alloc(120ull*10*64*8/2);
  unsigned short* imapB = (unsigned short*)alloc(9600ull*512/2);
  unsigned* t2pp = (unsigned*)alloc(512*256);
  float* xWfb  = alloc(64ull*30*1024);
  float* xWbb  = alloc(64ull*30*1024);
  float* lout  = alloc(64ull*30*512);
  float* qbuf  = alloc(64*512);
  float* stck  = alloc(64*150*8);
  float* pvecA = alloc(64*8);
  float* pvecB = alloc(64*8);
  float* memb  = alloc(64*512);
  float* cprev = alloc(64*512);
  float* tmp1a = alloc(9ull*64*512);
  float* ubuf  = alloc(64*512);
  float* wmw   = alloc(64*9);
  float* impp  = alloc(9*64);
  float* swb   = alloc(48);
  float* pl    = alloc(9ull*2*64*512);
  float* tmapv = alloc(64*512);
  float* h1b   = alloc(64*1024);
  uint4* whp4  = (uint4*)alloc(2*32*1024*4);

  // one dispatch: init + ALL independent packs
  megapack_k<<<5124, 256, 0, stream>>>(
      c0, c3ow, c4ow, aow, stck, pvecA, memb, cprev, swb, pl,
      Wh_f, Wh_b, whp4,
      ic1w, w1p, ic2w, w2mp, i2mw, w3mp, Wi_f, wifp, Wi_b, wibp,
      image, imgP, embedW, ques, embp, t2mw, t2pp);

  // conv chain (MFMA); conv3 -> bf16 row-major imapB
  gemmM_k<<<dim3(8,150,1), 256, 0, stream>>>(imgP, imgP, w1p, w1p, ic1b, ic1b,
                                             X1p, X1p, 20, 32, 512, 1, 1, 16);
  gemmM_k<<<dim3(8,150,1), 256, 0, stream>>>(X1p, X1p, w2mp, w2mp, ic2b, ic2b,
                                             X2p, X2p, 16, 32, 512, 1, 0, 16);
  gemmM_k<<<dim3(8,150,1), 256, 0, stream>>>(X2p, X2p, w3mp, w3mp, i2mb, i2mb,
                                             imapB, imapB, 16, 32, 512, 2, 0, 0);
  // both embed GEMMs in one launch (z = 0: fwd, z = 1: bwd)
  gemmM_k<<<dim3(16,30,2), 256, 0, stream>>>(embp, embp, wifp, wibp, b_f, b_b,
                                             xWfb, xWbb, 10, 64, 1024, 0, 0, 0);

  lstm4_k<<<128, 1024, 0, stream>>>(xWfb, xWbb, whp4, qlen, lout, qbuf);

  // tmp1all[t] = q @ W1[t] + b1 (all 9 t)
  gemm64b_k<<<dim3(8,8,9), 512, 0, stream>>>(
      qbuf, 0, 9, (const float*)nullptr, 0,
      W1, 262144, b1, 0, tmp1a, 32768, 512, 0);
  // u for t=0
  gemm64b_k<<<dim3(8,8,1), 512, 0, stream>>>(
      tmp1a, 0, 9, cprev, 512, W2w, 0, W2b, 0, ubuf, 0, 512, 0);

  for (int t = 0; t < 9; ++t) {
    float* pvIn  = (t & 1) ? pvecB : pvecA;
    float* pvOut = (t & 1) ? pvecA : pvecB;
    kcattn2_k<<<64, 256, 0, stream>>>(ubuf, Wmod, lout, W3, t2pp, t2mb,
                                      wmw, impp, cprev, tmapv, t);
    modules2_k<<<dim3(64,19), 256, 0, stream>>>(
        imapB, tmapv, stck, pvIn, pvOut, swb, c3cw, c3cb, c4cw, c4cb, wmw,
        pl + (size_t)t*65536);
    ansu_k<<<dim3(8,8), 512, 0, stream>>>(
        pl + (size_t)t*65536, tmapv, ansW, ansb, wmw, memb,
        tmp1a + (size_t)(t < 8 ? t+1 : 0)*32768, cprev, W2w, W2b, ubuf,
        (t < 8) ? 1 : 0);
  }

  // h1 = elu([q, mem] @ out1 + b);  logits = h1 @ out2 + b
  gemm64b_k<<<dim3(16,8,1), 512, 0, stream>>>(
      qbuf, 0, 9, memb, 512, o1w, 0, o1b, 0, h1b, 0, 1024, 1);
  gemm64b_k<<<dim3(1,8,1), 512, 0, stream>>>(
      h1b, 0, 10, (const float*)nullptr, 0, o2w, 0, o2b, 0, out, 0, 32, 0);
  imp_k<<<1, 256, 0, stream>>>(impp, out + 2048);
}

// Round 9
// 915.186 us; speedup vs baseline: 1.4615x; 1.2655x over previous
//
#include <hip/hip_runtime.h>
#include <math.h>

#define DEV __device__ __forceinline__

DEV float fexp(float x){ return __expf(x); }
DEV float elu_(float x){ return x > 0.f ? x : fexp(x) - 1.f; }
DEV float sigm_(float x){ return 1.f/(1.f + fexp(-x)); }
DEV float tanh_(float x){ float e = fexp(2.f*x); return 1.f - 2.f/(e + 1.f); }
DEV unsigned bf16r(float x){ unsigned u = __float_as_uint(x);
  return (u + 0x7fffu + ((u>>16)&1u)) >> 16; }
DEV float blo(unsigned u){ return __uint_as_float(u << 16); }
DEV float bhi(unsigned u){ return __uint_as_float(u & 0xffff0000u); }
DEV float bl(unsigned short u){ return __uint_as_float(((unsigned)u) << 16); }

using frag  = __attribute__((ext_vector_type(8))) short;   // 8 bf16 (4 VGPRs)
using f32x4 = __attribute__((ext_vector_type(4))) float;   // MFMA acc

// ---------------------------------------------------------------------------
// device pack helpers
// ---------------------------------------------------------------------------
DEV void d_pack4(const float* __restrict__ Whf, const float* __restrict__ Whb,
                 uint4* __restrict__ whp4, int idx)
{
  int dir = idx >> 15;
  int rem = idx & 32767;
  int kg  = rem >> 10;
  int n   = rem & 1023;
  const float* Wh = dir ? Whb : Whf;
  unsigned v[4];
#pragma unroll
  for (int j = 0; j < 4; ++j) {
    int k = kg*8 + 2*j;
    float lo = Wh[(size_t)k*1024 + n];
    float hi = Wh[(size_t)(k+1)*1024 + n];
    v[j] = bf16r(lo) | (bf16r(hi) << 16);
  }
  whp4[idx] = make_uint4(v[0], v[1], v[2], v[3]);
}

DEV void d_packB(const float* __restrict__ W, short* __restrict__ Bp,
                 int KC, int Ng, int Ksrc, int N, int trans, int idx)
{
  if (idx >= KC*Ng*64) return;
  int lane = idx & 63;
  int g    = (idx >> 6) % Ng;
  int kc   = idx / (64*Ng);
  int n = g*16 + (lane & 15);
  int kb = kc*32 + ((lane >> 4) << 3);
  unsigned o[4];
#pragma unroll
  for (int jj = 0; jj < 4; ++jj) {
    int k0 = kb + 2*jj;
    float v0 = (k0   < Ksrc) ? (trans ? W[(size_t)n*Ksrc + k0]   : W[(size_t)(k0)*N + n])   : 0.f;
    float v1 = (k0+1 < Ksrc) ? (trans ? W[(size_t)n*Ksrc + k0+1] : W[(size_t)(k0+1)*N + n]) : 0.f;
    o[jj] = bf16r(v0) | (bf16r(v1) << 16);
  }
  *(uint4*)(Bp + (size_t)idx*8) = make_uint4(o[0], o[1], o[2], o[3]);
}

DEV void d_packImg(const float* __restrict__ image, short* __restrict__ Ap, int idx)
{
  int lane = idx & 63;
  int kc   = (idx >> 6) % 20;
  int mt   = idx / 1280;
  int row = mt*16 + (lane & 15);
  int b = row / 150, p = row % 150;
  int cb = kc*32 + ((lane >> 4) << 3);
  unsigned o[4];
#pragma unroll
  for (int jj = 0; jj < 4; ++jj) {
    float v0 = image[((size_t)b*640 + cb + 2*jj    )*150 + p];
    float v1 = image[((size_t)b*640 + cb + 2*jj + 1)*150 + p];
    o[jj] = bf16r(v0) | (bf16r(v1) << 16);
  }
  *(uint4*)(Ap + (size_t)idx*8) = make_uint4(o[0], o[1], o[2], o[3]);
}

DEV void d_packEmb(const float* __restrict__ embedW, const int* __restrict__ ques,
                   short* __restrict__ Ap, int idx)
{
  int lane = idx & 63;
  int kc   = (idx >> 6) % 10;
  int mt   = idx / 640;
  int row = mt*16 + (lane & 15);
  int q = ques[row];
  int kb = kc*32 + ((lane >> 4) << 3);
  unsigned o[4];
#pragma unroll
  for (int jj = 0; jj < 4; ++jj) {
    int k0 = kb + 2*jj;
    float v0 = (k0   < 300) ? embedW[(size_t)q*300 + k0]   : 0.f;
    float v1 = (k0+1 < 300) ? embedW[(size_t)q*300 + k0+1] : 0.f;
    o[jj] = bf16r(v0) | (bf16r(v1) << 16);
  }
  *(uint4*)(Ap + (size_t)idx*8) = make_uint4(o[0], o[1], o[2], o[3]);
}

// ---------------------------------------------------------------------------
// ONE dispatch for all independent pre-stage work
// [0,320) init  [320,576) Wh  [576,736) ic1w  [736,864) ic2w  [864,992) i2mw
// [992,1152) Wi_f  [1152,1312) Wi_b  [1312,4312) img  [4312,4612) emb
// [4612,5124) t2m  [5124,7172) W2 bf16  [7172,11268) ansW bf16
// ---------------------------------------------------------------------------
__global__ __launch_bounds__(256)
void megapack_k(const float* __restrict__ c0, const float* __restrict__ c3ow,
                const float* __restrict__ c4ow, const float* __restrict__ aow,
                float* __restrict__ stack, float* __restrict__ pvecA,
                float* __restrict__ mem, float* __restrict__ cprev,
                float* __restrict__ swb, float* __restrict__ pl,
                const float* __restrict__ Whf, const float* __restrict__ Whb,
                uint4* __restrict__ whp4,
                const float* __restrict__ ic1w, short* __restrict__ w1p,
                const float* __restrict__ ic2w, short* __restrict__ w2mp,
                const float* __restrict__ i2mw, short* __restrict__ w3mp,
                const float* __restrict__ Wif, short* __restrict__ wifp,
                const float* __restrict__ Wib, short* __restrict__ wibp,
                const float* __restrict__ image, short* __restrict__ imgP,
                const float* __restrict__ embedW, const int* __restrict__ ques,
                short* __restrict__ embp,
                const float* __restrict__ t2mw, unsigned* __restrict__ t2pp,
                const float* __restrict__ W2w, unsigned short* __restrict__ w2bp,
                const float* __restrict__ ansW, unsigned short* __restrict__ answp)
{
  const int bx = blockIdx.x, tid = threadIdx.x;
  if (bx < 320) {
    int idx = bx*256 + tid;
    int stride = 320*256;
    for (int i = idx; i < 64*150*8; i += stride) stack[i] = 0.f;
    for (int i = idx; i < 64*8;    i += stride) pvecA[i] = ((i & 7) == 0) ? 1.f : 0.f;
    for (int i = idx; i < 64*512;  i += stride) mem[i] = 0.f;
    for (int i = idx; i < 64*512;  i += stride) cprev[i] = c0[i & 511];
    for (int i = idx; i < 9*2*64*512; i += stride) pl[i] = 0.f;
    if (idx < 8) {
      const float* ow = (idx < 4) ? (c3ow + idx*6)
                      : (idx < 6) ? (c4ow + (idx-4)*6)
                                  : (aow  + (idx-6)*6);
      float mx = ow[0];
      for (int m = 1; m < 6; ++m) mx = fmaxf(mx, ow[m]);
      float e[6]; float s = 0.f;
      for (int m = 0; m < 6; ++m) { e[m] = fexp(ow[m]-mx); s += e[m]; }
      for (int m = 0; m < 6; ++m) swb[idx*6+m] = e[m]/s;
    }
  } else if (bx < 576) {
    d_pack4(Whf, Whb, whp4, (bx-320)*256 + tid);
  } else if (bx < 736) {
    d_packB(ic1w, w1p, 20, 32, 640, 512, 1, (bx-576)*256 + tid);
  } else if (bx < 864) {
    d_packB(ic2w, w2mp, 16, 32, 512, 512, 1, (bx-736)*256 + tid);
  } else if (bx < 992) {
    d_packB(i2mw, w3mp, 16, 32, 512, 512, 1, (bx-864)*256 + tid);
  } else if (bx < 1152) {
    d_packB(Wif, wifp, 10, 64, 300, 1024, 0, (bx-992)*256 + tid);
  } else if (bx < 1312) {
    d_packB(Wib, wibp, 10, 64, 300, 1024, 0, (bx-1152)*256 + tid);
  } else if (bx < 4312) {
    d_packImg(image, imgP, (bx-1312)*256 + tid);
  } else if (bx < 4612) {
    d_packEmb(embedW, ques, embp, (bx-4312)*256 + tid);
  } else if (bx < 5124) {
    int idx = (bx-4612)*256 + tid;   // 512*256
    int k = idx >> 8, c = idx & 255;
    t2pp[idx] = bf16r(t2mw[(size_t)k*512 + c]) | (bf16r(t2mw[(size_t)k*512 + 256 + c]) << 16);
  } else if (bx < 7172) {
    int i = (bx-5124)*256 + tid;     // 524288
    w2bp[i] = (unsigned short)bf16r(W2w[i]);
  } else {
    int i = (bx-7172)*256 + tid;     // 1048576
    answp[i] = (unsigned short)bf16r(ansW[i]);
  }
}

// ---------------------------------------------------------------------------
// MFMA GEMM, dual problem sets via blockIdx.z.
// mode 0: fp32 row-major; mode 1: bf16 A-pack; mode 2: bf16 row-major
// ---------------------------------------------------------------------------
__global__ __launch_bounds__(256)
void gemmM_k(const short* __restrict__ ApA, const short* __restrict__ ApB,
             const short* __restrict__ BpA, const short* __restrict__ BpB,
             const float* __restrict__ biasA, const float* __restrict__ biasB,
             void* __restrict__ CoutA, void* __restrict__ CoutB,
             int KC, int Ng, int N, int mode, int act, int KCout)
{
  __shared__ float lds[4][16][68];
  const int z = blockIdx.z;
  const short* Ap = z ? ApB : ApA;
  const short* Bp = z ? BpB : BpA;
  const float* bias = z ? biasB : biasA;
  void* Cout = z ? CoutB : CoutA;
  const int tid = threadIdx.x, lane = tid & 63, w = tid >> 6;
  const int mt = blockIdx.y*4 + w;
  const int ncol0 = blockIdx.x*64;
  const short* Abase = Ap + (((size_t)mt*KC) << 9) + lane*8;
  const short* Bbase = Bp + (((size_t)blockIdx.x*4) << 9) + lane*8;
  f32x4 acc0 = {0.f,0.f,0.f,0.f}, acc1 = acc0, acc2 = acc0, acc3 = acc0;
#pragma unroll 2
  for (int kc = 0; kc < KC; ++kc) {
    frag a = *(const frag*)(Abase + ((size_t)kc << 9));
    const short* bk = Bbase + (((size_t)kc*Ng) << 9);
    frag b0 = *(const frag*)(bk);
    frag b1 = *(const frag*)(bk + 512);
    frag b2 = *(const frag*)(bk + 1024);
    frag b3 = *(const frag*)(bk + 1536);
    acc0 = __builtin_amdgcn_mfma_f32_16x16x32_bf16(a, b0, acc0, 0, 0, 0);
    acc1 = __builtin_amdgcn_mfma_f32_16x16x32_bf16(a, b1, acc1, 0, 0, 0);
    acc2 = __builtin_amdgcn_mfma_f32_16x16x32_bf16(a, b2, acc2, 0, 0, 0);
    acc3 = __builtin_amdgcn_mfma_f32_16x16x32_bf16(a, b3, acc3, 0, 0, 0);
  }
  {
    int colb = lane & 15, rowb = (lane >> 4)*4;
#pragma unroll
    for (int r = 0; r < 4; ++r) {
      lds[w][rowb+r][ 0+colb] = acc0[r];
      lds[w][rowb+r][16+colb] = acc1[r];
      lds[w][rowb+r][32+colb] = acc2[r];
      lds[w][rowb+r][48+colb] = acc3[r];
    }
  }
  __syncthreads();
  if (mode == 0) {
    float* C = (float*)Cout;
    int mloc = lane >> 2, q4 = lane & 3;
    size_t rowoff = (size_t)(mt*16 + mloc)*N + ncol0 + q4*16;
#pragma unroll
    for (int i = 0; i < 4; ++i) {
      float4 v = *(float4*)&lds[w][mloc][q4*16 + i*4];
      const float* bp = bias + ncol0 + q4*16 + i*4;
      v.x += bp[0]; v.y += bp[1]; v.z += bp[2]; v.w += bp[3];
      if (act) { v.x = elu_(v.x); v.y = elu_(v.y); v.z = elu_(v.z); v.w = elu_(v.w); }
      *(float4*)&C[rowoff + i*4] = v;
    }
  } else if (mode == 1) {
    short* C = (short*)Cout;
    int m = lane & 15, qb = (lane >> 4)*8;
#pragma unroll
    for (int h = 0; h < 2; ++h) {
      int nl = h*32 + qb;
      unsigned o[4];
#pragma unroll
      for (int jj = 0; jj < 4; ++jj) {
        float v0 = lds[w][m][nl + 2*jj]     + bias[ncol0 + nl + 2*jj];
        float v1 = lds[w][m][nl + 2*jj + 1] + bias[ncol0 + nl + 2*jj + 1];
        if (act) { v0 = elu_(v0); v1 = elu_(v1); }
        o[jj] = bf16r(v0) | (bf16r(v1) << 16);
      }
      *(uint4*)(C + (((size_t)mt*KCout + (ncol0 >> 5) + h) << 9) + lane*8)
          = make_uint4(o[0], o[1], o[2], o[3]);
    }
  } else {
    unsigned short* C = (unsigned short*)Cout;
    int row = lane >> 2, cb = (lane & 3)*16;
#pragma unroll
    for (int h = 0; h < 2; ++h) {
      unsigned o[4];
#pragma unroll
      for (int jj = 0; jj < 4; ++jj) {
        float v0 = lds[w][row][cb + h*8 + 2*jj]     + bias[ncol0 + cb + h*8 + 2*jj];
        float v1 = lds[w][row][cb + h*8 + 2*jj + 1] + bias[ncol0 + cb + h*8 + 2*jj + 1];
        if (act) { v0 = elu_(v0); v1 = elu_(v1); }
        o[jj] = bf16r(v0) | (bf16r(v1) << 16);
      }
      *(uint4*)&C[(size_t)(mt*16 + row)*N + ncol0 + cb + h*8]
          = make_uint4(o[0], o[1], o[2], o[3]);
    }
  }
}

// ---------------------------------------------------------------------------
// 64-row batch GEMM, K-split across waves
// ---------------------------------------------------------------------------
__global__ __launch_bounds__(512)
void gemm64b_k(const float* __restrict__ A1, long zA1, int K1log,
               const float* __restrict__ A2, int K2,
               const float* __restrict__ B, long zB,
               const float* __restrict__ bias, int zbias,
               float* __restrict__ C, long zC, int N, int act)
{
  const int K1 = 1 << K1log;
  const int Kt = K1 + K2;
  __shared__ __align__(16) float As[8][1024];
  __shared__ float part[8][8][64];
  const int tid = threadIdx.x;
  const int z = blockIdx.z;
  const int r0 = blockIdx.y*8;
  {
    const float* a1 = A1 + (size_t)z*zA1;
    const int nf4 = (8*K1) >> 2;
    for (int e4 = tid; e4 < nf4; e4 += 512) {
      int r = e4 >> (K1log-2);
      int k4 = (e4 & ((K1>>2)-1)) << 2;
      *(float4*)&As[r][k4] = *(const float4*)&a1[(size_t)(r0+r)*K1 + k4];
    }
    if (K2 > 0) {
      for (int e4 = tid; e4 < 1024; e4 += 512) {
        int r = e4 >> 7;
        int k4 = (e4 & 127) << 2;
        *(float4*)&As[r][K1+k4] = *(const float4*)&A2[(size_t)(r0+r)*512 + k4];
      }
    }
  }
  __syncthreads();
  const int lane = tid & 63, w = tid >> 6;
  const int n = blockIdx.x*64 + lane;
  const bool nv = n < N;
  const int kseg = Kt >> 3;
  const int k0 = w*kseg;
  const float* Bp = B + (size_t)z*zB + (size_t)k0*N + (nv ? n : 0);
  float acc[8] = {0,0,0,0,0,0,0,0};
#pragma unroll 8
  for (int kk = 0; kk < kseg; ++kk) {
    float bv = nv ? Bp[(size_t)kk*N] : 0.f;
    int k = k0 + kk;
#pragma unroll
    for (int r = 0; r < 8; ++r) acc[r] += As[r][k]*bv;
  }
#pragma unroll
  for (int r = 0; r < 8; ++r) part[w][r][lane] = acc[r];
  __syncthreads();
  {
    int r = tid >> 6, c = tid & 63;
    int nn = blockIdx.x*64 + c;
    if (nn < N) {
      float s = 0.f;
#pragma unroll
      for (int w2 = 0; w2 < 8; ++w2) s += part[w2][r][c];
      s += bias ? bias[(size_t)z*zbias + nn] : 0.f;
      if (act == 1) s = elu_(s);
      C[(size_t)z*zC + (size_t)(r0+r)*N + nn] = s;
    }
  }
}

// ---------------------------------------------------------------------------
// bidirectional masked LSTM; 128 blocks = (dir, batch)
// ---------------------------------------------------------------------------
__global__ __launch_bounds__(1024)
void lstm4_k(const float* __restrict__ xWf, const float* __restrict__ xWb,
             const uint4* __restrict__ whp4,
             const int* __restrict__ qlen, float* __restrict__ lstm_out,
             float* __restrict__ qout)
{
  int dir = blockIdx.x >> 6;
  int b   = blockIdx.x & 63;
  const float* xW = dir ? xWb : xWf;
  const uint4* Wp = whp4 + (size_t)dir*32768 + threadIdx.x;
  __shared__ __align__(16) float hl[256];
  __shared__ __align__(16) float cl[256];
  __shared__ float zl[1024];
  int tid = threadIdx.x;
  if (tid < 256) { hl[tid] = 0.f; cl[tid] = 0.f; }
  int len = qlen[b];
  for (int ss = 0; ss < 30; ++ss) {
    int s = dir ? (29-ss) : ss;
    __syncthreads();
    float z = xW[((size_t)b*30 + s)*1024 + tid];
#pragma unroll 4
    for (int kg = 0; kg < 32; ++kg) {
      uint4 w = Wp[(size_t)kg*1024];
      float4 ha = *(const float4*)&hl[kg*8];
      float4 hb = *(const float4*)&hl[kg*8+4];
      z += ha.x*blo(w.x) + ha.y*bhi(w.x) + ha.z*blo(w.y) + ha.w*bhi(w.y)
         + hb.x*blo(w.z) + hb.y*bhi(w.z) + hb.z*blo(w.w) + hb.w*bhi(w.w);
    }
    zl[tid] = z;
    __syncthreads();
    if (tid < 256) {
      float iv = zl[tid], fv = zl[256+tid], gv = zl[512+tid], ov = zl[768+tid];
      float cn = sigm_(fv)*cl[tid] + sigm_(iv)*tanh_(gv);
      float hn = sigm_(ov)*tanh_(cn);
      bool m = s < len;
      lstm_out[((size_t)b*30 + s)*512 + dir*256 + tid] = m ? hn : 0.f;
      if (m) { hl[tid] = hn; cl[tid] = cn; }
    }
  }
  __syncthreads();
  if (tid < 256) qout[(size_t)b*512 + dir*256 + tid] = hl[tid];
}

// ---------------------------------------------------------------------------
// fused kc + attn + tmap — 1024 threads (4x latency hiding on the GEMV tails)
// ---------------------------------------------------------------------------
__global__ __launch_bounds__(1024)
void kcattn3_k(const float* __restrict__ u, const float* __restrict__ Wmod,
               const float* __restrict__ lstm_out, const float* __restrict__ W3,
               const unsigned* __restrict__ t2pp, const float* __restrict__ t2mb,
               float* __restrict__ woutAll, float* __restrict__ imp_part,
               float* __restrict__ cout, float* __restrict__ tmapv, int t)
{
  int b = blockIdx.x;
  int tid = threadIdx.x;
  int lane = tid & 63, wave = tid >> 6;   // 16 waves
  __shared__ float ush[512];
  __shared__ float sC[512];
  __shared__ float cpart[512];
  __shared__ float tpart[4][512];
  __shared__ float wl[9];
  __shared__ float sc[32], at[32];
  if (tid < 512) ush[tid] = u[b*512 + tid];
  __syncthreads();
  // attention scores (16 waves cover s = wave, wave+16)
  for (int s = wave; s < 30; s += 16) {
    float acc = 0.f;
    const float* lo = lstm_out + ((size_t)b*30 + s)*512;
#pragma unroll
    for (int h = lane; h < 512; h += 64) acc += lo[h]*ush[h]*W3[h];
#pragma unroll
    for (int off = 32; off; off >>= 1) acc += __shfl_down(acc, off);
    if (lane == 0) sc[s] = acc;
  }
  // kernel-choice logits (waves 0..8, one m each)
  if (wave < 9) {
    float acc = 0.f;
#pragma unroll
    for (int k = lane; k < 512; k += 64) acc += ush[k]*Wmod[k*9+wave];
#pragma unroll
    for (int off = 32; off; off >>= 1) acc += __shfl_down(acc, off);
    if (lane == 0) wl[wave] = acc;
  }
  __syncthreads();
  if (tid == 0) {
    float mx = wl[0];
    for (int m = 1; m < 9; ++m) mx = fmaxf(mx, wl[m]);
    float s = 0.f;
    for (int m = 0; m < 9; ++m) s += fexp(wl[m]-mx);
    float ls = logf(s);
    float ent = 0.f;
    for (int m = 0; m < 9; ++m) {
      float l = wl[m]-mx-ls;
      float w = fexp(l);
      woutAll[t*576 + b*9 + m] = w;
      ent -= w*l;
    }
    imp_part[t*64+b] = ent;
  }
  if (wave == 1) {
    float v = (lane < 30) ? sc[lane] : -3.4e38f;
    float mx = v;
#pragma unroll
    for (int off = 32; off; off >>= 1) mx = fmaxf(mx, __shfl_xor(mx, off));
    float e = (lane < 30) ? fexp(v-mx) : 0.f;
    float ssum = e;
#pragma unroll
    for (int off = 32; off; off >>= 1) ssum += __shfl_xor(ssum, off);
    if (lane < 30) at[lane] = e/ssum;
  }
  __syncthreads();
  // context: 2-way s-split per h
  {
    int h = tid & 511, seg = tid >> 9;
    float acc = 0.f;
    int s0 = seg ? 15 : 0, s1 = seg ? 30 : 15;
    for (int s = s0; s < s1; ++s) acc += at[s]*lstm_out[((size_t)b*30 + s)*512 + h];
    if (seg) cpart[h] = acc;
    __syncthreads();
    if (!seg) {
      float tot = acc + cpart[h];
      cout[b*512+h] = tot;
      sC[h] = tot;
    }
  }
  __syncthreads();
  // tmap = c @ t2m + b  (pair-packed bf16; 4-way k-split)
  {
    int c2 = tid & 255, ks = tid >> 8;   // ks in 0..3
    float a0 = 0.f, a1 = 0.f;
    const unsigned* tp = t2pp + c2;
#pragma unroll 8
    for (int k = ks*128; k < ks*128 + 128; ++k) {
      float cv = sC[k];
      unsigned wv2 = tp[(size_t)k*256];
      a0 += cv*blo(wv2);
      a1 += cv*bhi(wv2);
    }
    tpart[ks][c2]       = a0;
    tpart[ks][256 + c2] = a1;
  }
  __syncthreads();
  if (tid < 512) {
    float v = tpart[0][tid] + tpart[1][tid] + tpart[2][tid] + tpart[3][tid];
    tmapv[b*512 + tid] = v + t2mb[tid];
  }
}

// ---------------------------------------------------------------------------
// fused modules + pooled partials (atomicAdd into per-t pl buffer) + stack
// update + pvec ping-pong.  grid (64 b, 19 pb).
// ---------------------------------------------------------------------------
__global__ __launch_bounds__(256)
void modules2_k(const unsigned short* __restrict__ imapB, const float* __restrict__ tmapv,
                float* __restrict__ stack, const float* __restrict__ pvecIn,
                float* __restrict__ pvecOut,
                const float* __restrict__ swb, const float* __restrict__ c3w,
                const float* __restrict__ c3b, const float* __restrict__ c4w,
                const float* __restrict__ c4b, const float* __restrict__ wmod,
                float* __restrict__ plt)
{
  int b  = blockIdx.x;
  int pb = blockIdx.y;
  int lane = threadIdx.x & 63, wave = threadIdx.x >> 6;
  __shared__ float sT[512];
  __shared__ float pv[8], pd[8], wm[9];
  __shared__ float wpart[4][2][512];
  for (int j = threadIdx.x; j < 512; j += 256) sT[j] = tmapv[b*512 + j];
  if (threadIdx.x < 8) pv[threadIdx.x] = pvecIn[b*8+threadIdx.x];
  if (threadIdx.x >= 64 && threadIdx.x < 73) wm[threadIdx.x-64] = wmod[b*9 + threadIdx.x-64];
  __syncthreads();
  if (threadIdx.x < 8) {
    int l = threadIdx.x;
    pd[l] = (l < 7 ? pv[l+1] : 0.f) + (l == 0 ? pv[0] : 0.f);
  }
  __syncthreads();
  if (pb == 0 && threadIdx.x < 8) {
    int l = threadIdx.x;
    float WP = wm[0]+wm[1]+wm[2]+wm[3] + wm[6] + wm[8];
    float WD = wm[4]+wm[5] + wm[7];
    pvecOut[b*8+l] = WP*pv[l] + WD*pd[l];
  }

  float W[8][6];
#pragma unroll
  for (int m = 0; m < 8; ++m)
#pragma unroll
    for (int i = 0; i < 6; ++i) W[m][i] = swb[m*6+i];
  float W03 = wm[0]+wm[1]+wm[2]+wm[3];
  float W45 = wm[4]+wm[5];

  float acc6[8], acc7[8];
#pragma unroll
  for (int i = 0; i < 8; ++i) { acc6[i] = 0.f; acc7[i] = 0.f; }

  for (int pi = 0; pi < 2; ++pi) {
    int p = pb*8 + wave*2 + pi;
    if (p < 150) {
      const float* st = stack + ((size_t)b*150 + p)*8;
      float a = 0.f, av2 = 0.f;
#pragma unroll
      for (int l = 0; l < 8; ++l) { float v = st[l]; a += v*pv[l]; av2 += v*pd[l]; }
      float part[6] = {0,0,0,0,0,0};
#pragma unroll 2
      for (int i = 0; i < 8; ++i) {
        int d = i*64 + lane;
        float x = bl(imapB[((size_t)b*150 + p)*512 + d]);
        float t = sT[d];
#pragma unroll
        for (int m = 0; m < 4; ++m) {
          float c1 = W[m][0]*t + W[m][1] + W[m][4] + (W[m][2] + W[m][3]*t)*a;
          float c0 = W[m][1]*t + W[m][5]*t*a;
          part[m] += elu_(c1*x + c0) * c3w[m*512+d];
        }
#pragma unroll
        for (int m = 0; m < 2; ++m) {
          float c1 = W[4+m][0]*t + W[4+m][1] + W[4+m][2]*a + W[4+m][3]*av2
                   + W[4+m][4]*a*av2 + W[4+m][5]*t*(a+av2);
          part[4+m] += elu_(c1*x + W[4+m][1]*t) * c4w[m*512+d];
        }
        float c16 = W[6][0]*t + W[6][1] + W[6][4] + (W[6][2] + W[6][3]*t)*a;
        float c06 = W[6][1]*t + W[6][5]*t*a;
        acc6[i] += elu_(c16*x + c06);
        float c17 = W[7][0]*t + W[7][1] + W[7][2]*a + W[7][3]*av2
                  + W[7][4]*a*av2 + W[7][5]*t*(a+av2);
        acc7[i] += elu_(c17*x + W[7][1]*t);
      }
#pragma unroll
      for (int m = 0; m < 6; ++m) {
#pragma unroll
        for (int off = 32; off; off >>= 1) part[m] += __shfl_down(part[m], off);
        part[m] = __shfl(part[m], 0);
      }
      float r3  = wm[0]*(part[0]+c3b[0]) + wm[1]*(part[1]+c3b[1])
                + wm[2]*(part[2]+c3b[2]) + wm[3]*(part[3]+c3b[3]);
      float r45 = wm[4]*(part[4]+c4b[0]) + wm[5]*(part[5]+c4b[1]);
      if (lane < 8) {
        int l = lane;
        size_t idx = ((size_t)b*150 + p)*8 + l;
        stack[idx] = stack[idx]*(1.f - W03*pv[l] - W45*pd[l])
                   + pv[l]*r3 + pd[l]*r45;
      }
    }
  }
#pragma unroll
  for (int i = 0; i < 8; ++i) {
    wpart[wave][0][i*64+lane] = acc6[i];
    wpart[wave][1][i*64+lane] = acc7[i];
  }
  __syncthreads();
  for (int e = threadIdx.x; e < 1024; e += 256) {
    int which = e >> 9, d = e & 511;
    float s = wpart[0][which][d] + wpart[1][which][d]
            + wpart[2][which][d] + wpart[3][which][d];
    atomicAdd(&plt[(size_t)which*32768 + b*512 + d], s * (1.f/150.f));
  }
}

// ---------------------------------------------------------------------------
// split ans/u GEMMs: grid (8 colchunks, 8 rowchunks, 3).
// z=0/1: m67o[z] = [pl_t[z]|tmap] @ ansW[z] + b (bf16 B).  z=2: next-t u GEMM.
// (mem blend deferred to memfin_k)
// ---------------------------------------------------------------------------
__global__ __launch_bounds__(512)
void ansu3_k(const float* __restrict__ plt, const float* __restrict__ tmapv,
             const unsigned short* __restrict__ answp, const float* __restrict__ ansb,
             float* __restrict__ m67o,
             const float* __restrict__ tmp1n, const float* __restrict__ cprev,
             const unsigned short* __restrict__ w2bp, const float* __restrict__ W2b,
             float* __restrict__ ubuf, int do_u)
{
  const int z = blockIdx.z;
  if (z == 2 && !do_u) return;
  __shared__ __align__(16) float As[8][1024];
  __shared__ float part[8][8][64];
  const int tid = threadIdx.x;
  const int r0 = blockIdx.y*8;
  const int nc0 = blockIdx.x*64;
  const int lane = tid & 63, w = tid >> 6;

  if (z < 2) {
    for (int e4 = tid; e4 < 1024; e4 += 512) {
      int r = e4 >> 7, k4 = (e4 & 127) << 2;
      *(float4*)&As[r][k4]     = *(const float4*)&plt[(size_t)z*32768 + (size_t)(r0+r)*512 + k4];
      *(float4*)&As[r][512+k4] = *(const float4*)&tmapv[(size_t)(r0+r)*512 + k4];
    }
  } else {
    for (int e4 = tid; e4 < 1024; e4 += 512) {
      int r = e4 >> 7, k4 = (e4 & 127) << 2;
      *(float4*)&As[r][k4]     = *(const float4*)&tmp1n[(size_t)(r0+r)*512 + k4];
      *(float4*)&As[r][512+k4] = *(const float4*)&cprev[(size_t)(r0+r)*512 + k4];
    }
  }
  __syncthreads();
  {
    const unsigned short* Bp = (z < 2 ? answp + (size_t)z*524288 : w2bp)
                             + (size_t)(w*128)*512 + nc0 + lane;
    float acc[8] = {0,0,0,0,0,0,0,0};
    int k0 = w*128;
#pragma unroll 8
    for (int kk = 0; kk < 128; ++kk) {
      float bv = bl(Bp[(size_t)kk*512]);
#pragma unroll
      for (int r = 0; r < 8; ++r) acc[r] += As[r][k0+kk]*bv;
    }
#pragma unroll
    for (int r = 0; r < 8; ++r) part[w][r][lane] = acc[r];
  }
  __syncthreads();
  {
    int r = tid >> 6, c = tid & 63;
    float s = 0.f;
#pragma unroll
    for (int w2 = 0; w2 < 8; ++w2) s += part[w2][r][c];
    if (z < 2) {
      m67o[((size_t)z*64 + r0 + r)*512 + nc0 + c] = s + ansb[z*512 + nc0 + c];
    } else {
      ubuf[(size_t)(r0+r)*512 + nc0 + c] = s + W2b[nc0 + c];
    }
  }
}

// ---------------------------------------------------------------------------
// final mem: mem_8 = sum_t coef_t*(w6_t*m6_t + w7_t*m7_t),
// coef_t = prod_{s>t} (1-w6_s-w7_s).  (mem_init = 0)
// ---------------------------------------------------------------------------
__global__ __launch_bounds__(512)
void memfin_k(const float* __restrict__ woutAll, const float* __restrict__ m67t,
              float* __restrict__ memb)
{
  int b = blockIdx.x;
  int tid = threadIdx.x;
  __shared__ float w6s[9], w7s[9], coef[9];
  if (tid < 9)       w6s[tid] = woutAll[tid*576 + b*9 + 6];
  else if (tid < 18) w7s[tid-9] = woutAll[(tid-9)*576 + b*9 + 7];
  __syncthreads();
  if (tid == 0) {
    float c = 1.f;
    for (int t = 8; t >= 0; --t) { coef[t] = c; c *= (1.f - w6s[t] - w7s[t]); }
  }
  __syncthreads();
  float acc = 0.f;
#pragma unroll
  for (int t = 0; t < 9; ++t) {
    float m6 = m67t[(((size_t)t*2 + 0)*64 + b)*512 + tid];
    float m7 = m67t[(((size_t)t*2 + 1)*64 + b)*512 + tid];
    acc += coef[t]*(w6s[t]*m6 + w7s[t]*m7);
  }
  memb[b*512 + tid] = acc;
}

// ---------------------------------------------------------------------------
__global__ __launch_bounds__(256)
void imp_k(const float* __restrict__ part, float* __restrict__ out)
{
  int lane = threadIdx.x & 63, wave = threadIdx.x >> 6;
  float acc = 0.f;
  for (int i = threadIdx.x; i < 576; i += 256) acc += part[i];
#pragma unroll
  for (int off = 32; off; off >>= 1) acc += __shfl_down(acc, off);
  __shared__ float red[4];
  if (lane == 0) red[wave] = acc;
  __syncthreads();
  if (threadIdx.x == 0) out[0] = red[0]+red[1]+red[2]+red[3];
}

// ---------------------------------------------------------------------------
extern "C" void kernel_launch(void* const* d_in, const int* in_sizes, int n_in,
                              void* d_out, int out_size, void* d_ws, size_t ws_size,
                              hipStream_t stream)
{
  (void)in_sizes; (void)n_in; (void)out_size; (void)ws_size;
  const float* image = (const float*)d_in[0];
  const int*   ques  = (const int*)d_in[1];
  const int*   qlen  = (const int*)d_in[2];
  const float* embedW= (const float*)d_in[3];
  const float* Wi_f  = (const float*)d_in[4];
  const float* Wh_f  = (const float*)d_in[5];
  const float* b_f   = (const float*)d_in[6];
  const float* Wi_b  = (const float*)d_in[7];
  const float* Wh_b  = (const float*)d_in[8];
  const float* b_b   = (const float*)d_in[9];
  const float* W1    = (const float*)d_in[10];
  const float* b1    = (const float*)d_in[11];
  const float* W2w   = (const float*)d_in[12];
  const float* W2b   = (const float*)d_in[13];
  const float* W3    = (const float*)d_in[14];
  const float* c0    = (const float*)d_in[15];
  const float* Wmod  = (const float*)d_in[16];
  const float* ic1w  = (const float*)d_in[17];
  const float* ic1b  = (const float*)d_in[18];
  const float* ic2w  = (const float*)d_in[19];
  const float* ic2b  = (const float*)d_in[20];
  const float* i2mw  = (const float*)d_in[21];
  const float* i2mb  = (const float*)d_in[22];
  const float* t2mw  = (const float*)d_in[23];
  const float* t2mb  = (const float*)d_in[24];
  const float* c3ow  = (const float*)d_in[25];
  const float* c3cw  = (const float*)d_in[26];
  const float* c3cb  = (const float*)d_in[27];
  const float* c4ow  = (const float*)d_in[28];
  const float* c4cw  = (const float*)d_in[29];
  const float* c4cb  = (const float*)d_in[30];
  const float* aow   = (const float*)d_in[31];
  const float* ansW  = (const float*)d_in[32];
  const float* ansb  = (const float*)d_in[33];
  const float* o1w   = (const float*)d_in[34];
  const float* o1b   = (const float*)d_in[35];
  const float* o2w   = (const float*)d_in[36];
  const float* o2b   = (const float*)d_in[37];
  float* out = (float*)d_out;
  float* ws  = (float*)d_ws;

  size_t off = 0;
  auto alloc = [&](size_t n){ float* p = ws + off; off += n; return p; };
  short* imgP  = (short*)alloc(600ull*20*64*8/2);
  short* X1p   = (short*)alloc(600ull*16*64*8/2);
  short* X2p   = (short*)alloc(600ull*16*64*8/2);
  short* w1p   = (short*)alloc(20*32*64*8/2);
  short* w2mp  = (short*)alloc(16*32*64*8/2);
  short* w3mp  = (short*)alloc(16*32*64*8/2);
  short* wifp  = (short*)alloc(10*64*64*8/2);
  short* wibp  = (short*)alloc(10*64*64*8/2);
  short* embp  = (short*)alloc(120ull*10*64*8/2);
  unsigned short* imapB = (unsigned short*)alloc(9600ull*512/2);
  unsigned* t2pp = (unsigned*)alloc(512*256);
  unsigned short* w2bp  = (unsigned short*)alloc(524288/2);
  unsigned short* answp = (unsigned short*)alloc(1048576/2);
  float* xWfb  = alloc(64ull*30*1024);
  float* xWbb  = alloc(64ull*30*1024);
  float* lout  = alloc(64ull*30*512);
  float* qbuf  = alloc(64*512);
  float* stck  = alloc(64*150*8);
  float* pvecA = alloc(64*8);
  float* pvecB = alloc(64*8);
  float* memb  = alloc(64*512);
  float* cprev = alloc(64*512);
  float* tmp1a = alloc(9ull*64*512);
  float* ubuf  = alloc(64*512);
  float* wmwA  = alloc(9*64*9);
  float* impp  = alloc(9*64);
  float* swb   = alloc(48);
  float* pl    = alloc(9ull*2*64*512);
  float* m67t  = alloc(9ull*2*64*512);
  float* tmapv = alloc(64*512);
  float* h1b   = alloc(64*1024);
  uint4* whp4  = (uint4*)alloc(2*32*1024*4);

  // one dispatch: init + ALL independent packs (incl. bf16 W2/ansW)
  megapack_k<<<11268, 256, 0, stream>>>(
      c0, c3ow, c4ow, aow, stck, pvecA, memb, cprev, swb, pl,
      Wh_f, Wh_b, whp4,
      ic1w, w1p, ic2w, w2mp, i2mw, w3mp, Wi_f, wifp, Wi_b, wibp,
      image, imgP, embedW, ques, embp, t2mw, t2pp,
      W2w, w2bp, ansW, answp);

  // conv chain (MFMA); conv3 -> bf16 row-major imapB
  gemmM_k<<<dim3(8,150,1), 256, 0, stream>>>(imgP, imgP, w1p, w1p, ic1b, ic1b,
                                             X1p, X1p, 20, 32, 512, 1, 1, 16);
  gemmM_k<<<dim3(8,150,1), 256, 0, stream>>>(X1p, X1p, w2mp, w2mp, ic2b, ic2b,
                                             X2p, X2p, 16, 32, 512, 1, 0, 16);
  gemmM_k<<<dim3(8,150,1), 256, 0, stream>>>(X2p, X2p, w3mp, w3mp, i2mb, i2mb,
                                             imapB, imapB, 16, 32, 512, 2, 0, 0);
  // both embed GEMMs in one launch
  gemmM_k<<<dim3(16,30,2), 256, 0, stream>>>(embp, embp, wifp, wibp, b_f, b_b,
                                             xWfb, xWbb, 10, 64, 1024, 0, 0, 0);

  lstm4_k<<<128, 1024, 0, stream>>>(xWfb, xWbb, whp4, qlen, lout, qbuf);

  // tmp1all[t] = q @ W1[t] + b1 (all 9 t)
  gemm64b_k<<<dim3(8,8,9), 512, 0, stream>>>(
      qbuf, 0, 9, (const float*)nullptr, 0,
      W1, 262144, b1, 0, tmp1a, 32768, 512, 0);
  // u for t=0 (fp32 W2)
  gemm64b_k<<<dim3(8,8,1), 512, 0, stream>>>(
      tmp1a, 0, 9, cprev, 512, W2w, 0, W2b, 0, ubuf, 0, 512, 0);

  for (int t = 0; t < 9; ++t) {
    float* pvIn  = (t & 1) ? pvecB : pvecA;
    float* pvOut = (t & 1) ? pvecA : pvecB;
    kcattn3_k<<<64, 1024, 0, stream>>>(ubuf, Wmod, lout, W3, t2pp, t2mb,
                                       wmwA, impp, cprev, tmapv, t);
    modules2_k<<<dim3(64,19), 256, 0, stream>>>(
        imapB, tmapv, stck, pvIn, pvOut, swb, c3cw, c3cb, c4cw, c4cb,
        wmwA + (size_t)t*576, pl + (size_t)t*65536);
    ansu3_k<<<dim3(8,8,3), 512, 0, stream>>>(
        pl + (size_t)t*65536, tmapv, answp, ansb, m67t + (size_t)t*65536,
        tmp1a + (size_t)(t < 8 ? t+1 : 0)*32768, cprev, w2bp, W2b, ubuf,
        (t < 8) ? 1 : 0);
  }

  // final mem blend, then h1 = elu([q, mem] @ out1 + b); logits = h1 @ out2 + b
  memfin_k<<<64, 512, 0, stream>>>(wmwA, m67t, memb);
  gemm64b_k<<<dim3(16,8,1), 512, 0, stream>>>(
      qbuf, 0, 9, memb, 512, o1w, 0, o1b, 0, h1b, 0, 1024, 1);
  gemm64b_k<<<dim3(1,8,1), 512, 0, stream>>>(
      h1b, 0, 10, (const float*)nullptr, 0, o2w, 0, o2b, 0, out, 0, 32, 0);
  imp_k<<<1, 256, 0, stream>>>(impp, out + 2048);
}